// Round 3
// baseline (2422.662 us; speedup 1.0000x reference)
//
#include <hip/hip_runtime.h>
#include <math.h>

#define BQ 4
#define LQ 4096
#define DM 192
#define DIP 1030
#define DSSM 384
#define DST 128
#define CCH 646
#define NHD 6
#define KDIR 4
#define NCH 16
#define CLEN 256

__device__ __forceinline__ int pixof(int k, int t) {
  switch (k) {
    case 0: return t;
    case 1: return ((t & 63) << 6) | (t >> 6);
    case 2: return 4095 - t;
    default: { int tp = 4095 - t; return ((tp & 63) << 6) | (tp >> 6); }
  }
}

__device__ __forceinline__ float softplusf(float x) {
  return (x > 20.f) ? x : log1pf(expf(x));
}
__device__ __forceinline__ float siluf(float x) {
  return x / (1.f + expf(-x));
}

// ---- 1. in_proj GEMM: (B*L,192) @ (192,1030) -> z (384) | xbc (646) ----
__global__ void k_inproj(const float* __restrict__ u, const float* __restrict__ W,
                         float* __restrict__ zbuf, float* __restrict__ xbc) {
  __shared__ float s_u[8 * DM];
  int m0 = blockIdx.x * 8;
  int t = threadIdx.x;
  for (int e = t; e < 8 * DM; e += 256) s_u[e] = u[(size_t)m0 * DM + e];
  __syncthreads();
  for (int n = t; n < DIP; n += 256) {
    float acc[8];
#pragma unroll
    for (int r = 0; r < 8; ++r) acc[r] = 0.f;
    for (int kk = 0; kk < DM; ++kk) {
      float wv = W[(size_t)kk * DIP + n];
#pragma unroll
      for (int r = 0; r < 8; ++r) acc[r] += s_u[r * DM + kk] * wv;
    }
    if (n < DSSM) {
#pragma unroll
      for (int r = 0; r < 8; ++r) zbuf[(size_t)(m0 + r) * DSSM + n] = acc[r];
    } else {
#pragma unroll
      for (int r = 0; r < 8; ++r) xbc[(size_t)(m0 + r) * CCH + (n - DSSM)] = acc[r];
    }
  }
}

// ---- 2. depthwise 3x3 conv + bias + SiLU ----
__global__ void k_conv(const float* __restrict__ xbc, const float* __restrict__ cw,
                       const float* __restrict__ cb, float* __restrict__ convo) {
  int pid = blockIdx.x;  // b*4096 + p
  int b = pid >> 12, p = pid & 4095;
  int y = p >> 6, x = p & 63;
  int t = threadIdx.x;
  const float* base = xbc + (size_t)b * LQ * CCH;
  for (int c = t; c < CCH; c += 256) {
    float s = 0.f;
#pragma unroll
    for (int ky = 0; ky < 3; ++ky) {
      int yy = y + ky - 1;
      if (yy < 0 || yy > 63) continue;
#pragma unroll
      for (int kx = 0; kx < 3; ++kx) {
        int xx = x + kx - 1;
        if (xx < 0 || xx > 63) continue;
        s += base[(size_t)(yy * 64 + xx) * CCH + c] * cw[c * 9 + ky * 3 + kx];
      }
    }
    convo[(size_t)pid * CCH + c] = siluf(s + cb[c]);
  }
}

// ---- 3. dt softplus + per-chunk cumsum of dA ----
__global__ void k_prep(const float* __restrict__ convo, const float* __restrict__ dt_bias,
                       const float* __restrict__ A_logs,
                       float* __restrict__ dtb, float* __restrict__ dacb) {
  __shared__ float sb[CLEN];
  int z = blockIdx.x, k = blockIdx.y, b = blockIdx.z;
  int s = threadIdx.x;
  int pixel = pixof(k, z * CLEN + s);
  const float* row = convo + ((size_t)(b * LQ + pixel)) * CCH + (DSSM + 2 * DST);
  float raw[NHD];
#pragma unroll
  for (int h = 0; h < NHD; ++h) raw[h] = row[h];
  size_t base = (((size_t)(b * KDIR + k) * NCH + z) * NHD) * CLEN;
  for (int h = 0; h < NHD; ++h) {
    float dtv = softplusf(raw[h] + dt_bias[k * NHD + h]);
    float dA = dtv * (-expf(A_logs[k * NHD + h]));
    sb[s] = dA;
    __syncthreads();
    for (int off = 1; off < CLEN; off <<= 1) {
      float v = (s >= off) ? sb[s - off] : 0.f;
      __syncthreads();
      sb[s] += v;
      __syncthreads();
    }
    dtb[base + (size_t)h * CLEN + s] = dtv;
    dacb[base + (size_t)h * CLEN + s] = sb[s];
    __syncthreads();
  }
}

// ---- 4. CB = C @ B^T, lower-triangle 64x64 tiles, shared across heads ----
__global__ void k_cb(const float* __restrict__ convo, float* __restrict__ cbuf) {
  __shared__ float sC[64 * 33];
  __shared__ float sB[64 * 33];
  int pi = blockIdx.x;  // 0..9 tile pair
  int z = blockIdx.y;
  int bk = blockIdx.z;  // b*4 + k
  int b = bk >> 2, k = bk & 3;
  int SI = 0;
  while ((SI + 1) * (SI + 2) / 2 <= pi) ++SI;
  int SJ = pi - SI * (SI + 1) / 2;
  int t = threadIdx.x;
  int sj = t & 63;
  int g = t >> 6;
  float acc[16];
#pragma unroll
  for (int i = 0; i < 16; ++i) acc[i] = 0.f;
  for (int nt = 0; nt < 4; ++nt) {
    for (int e = t; e < 64 * 32; e += 256) {
      int ss = e >> 5, nn = e & 31;
      int pc = pixof(k, z * CLEN + SI * 64 + ss);
      sC[ss * 33 + nn] = convo[((size_t)(b * LQ + pc)) * CCH + (DSSM + DST) + nt * 32 + nn];
      int pb = pixof(k, z * CLEN + SJ * 64 + ss);
      sB[ss * 33 + nn] = convo[((size_t)(b * LQ + pb)) * CCH + DSSM + nt * 32 + nn];
    }
    __syncthreads();
    for (int nn = 0; nn < 32; ++nn) {
      float bv = sB[sj * 33 + nn];
#pragma unroll
      for (int i = 0; i < 16; ++i) acc[i] += sC[(g * 16 + i) * 33 + nn] * bv;
    }
    __syncthreads();
  }
  size_t base = ((size_t)(bk * NCH + z) * 10 + pi) * 4096;
#pragma unroll
  for (int i = 0; i < 16; ++i) cbuf[base + (g * 16 + i) * 64 + sj] = acc[i];
}

// ---- 5. chunk states: states[n][p] = sum_s B[s,n] * x[s,p]*dt[s]*exp(dAc_last-dAc[s]) ----
__global__ void k_states(const float* __restrict__ convo, const float* __restrict__ dtb,
                         const float* __restrict__ dacb, float* __restrict__ states) {
  __shared__ float sB[64 * 128];
  __shared__ float sX[64 * 64];
  __shared__ float sdt[CLEN];
  __shared__ float sdac[CLEN];
  int h = blockIdx.x, z = blockIdx.y, bk = blockIdx.z;
  int b = bk >> 2, k = bk & 3;
  int t = threadIdx.x;
  size_t dbase = (((size_t)bk * NCH + z) * NHD + h) * CLEN;
  sdt[t] = dtb[dbase + t];
  sdac[t] = dacb[dbase + t];
  __syncthreads();
  float dac_last = sdac[CLEN - 1];
  int p = t & 63;
  int nb = (t >> 6) * 32;
  float acc[32];
#pragma unroll
  for (int j = 0; j < 32; ++j) acc[j] = 0.f;
  for (int st = 0; st < 4; ++st) {
    for (int e = t; e < 64 * 128; e += 256) {
      int ss = e >> 7, nn = e & 127;
      int pp = pixof(k, z * CLEN + st * 64 + ss);
      sB[e] = convo[((size_t)(b * LQ + pp)) * CCH + DSSM + nn];
    }
    for (int e = t; e < 64 * 64; e += 256) {
      int ss = e >> 6, pp2 = e & 63;
      int sg = st * 64 + ss;
      int px = pixof(k, z * CLEN + sg);
      float xv = convo[((size_t)(b * LQ + px)) * CCH + h * 64 + pp2];
      sX[e] = xv * sdt[sg] * expf(dac_last - sdac[sg]);
    }
    __syncthreads();
    for (int ss = 0; ss < 64; ++ss) {
      float xv = sX[ss * 64 + p];
#pragma unroll
      for (int j = 0; j < 32; ++j) acc[j] += sB[ss * 128 + nb + j] * xv;
    }
    __syncthreads();
  }
  size_t sbase = (((size_t)bk * NCH + z) * NHD + h) * (128 * 64);
#pragma unroll
  for (int j = 0; j < 32; ++j) states[sbase + (size_t)(nb + j) * 64 + p] = acc[j];
}

// ---- 6. inter-chunk scan (in place: states -> prev states) ----
__global__ void k_scan(float* __restrict__ states, const float* __restrict__ dacb) {
  int h = blockIdx.x, k = blockIdx.y, b = blockIdx.z;
  int bk = b * KDIR + k;
  int t = threadIdx.x;
  float carry[32];
#pragma unroll
  for (int j = 0; j < 32; ++j) carry[j] = 0.f;
  for (int z = 0; z < NCH; ++z) {
    float cd = expf(dacb[(((size_t)bk * NCH + z) * NHD + h) * CLEN + (CLEN - 1)]);
    size_t sbase = (((size_t)bk * NCH + z) * NHD + h) * (128 * 64);
#pragma unroll
    for (int j = 0; j < 32; ++j) {
      size_t idx = sbase + (size_t)j * 256 + t;
      float sv = states[idx];
      states[idx] = carry[j];
      carry[j] = carry[j] * cd + sv;
    }
  }
}

// ---- 7. y = y_inter + y_intra + D*x, accumulated into output image ----
__global__ void k_y(const float* __restrict__ convo, const float* __restrict__ dtb,
                    const float* __restrict__ dacb, const float* __restrict__ cbuf,
                    const float* __restrict__ prevb, const float* __restrict__ Ds,
                    float* __restrict__ outpre) {
  __shared__ float sdt[CLEN];
  __shared__ float sdac[CLEN];
  __shared__ float sC[64 * 33];
  __shared__ float sP[32 * 64];
  __shared__ float sCB[64 * 64];
  __shared__ float sXW[64 * 64];
  int si_t = blockIdx.x & 3;  // SI tile
  int h = blockIdx.x >> 2;
  int z = blockIdx.y;
  int bk = blockIdx.z;
  int b = bk >> 2, k = bk & 3;
  int t = threadIdx.x;
  int p = t & 63;
  int qr = t >> 6;
  size_t dbase = (((size_t)bk * NCH + z) * NHD + h) * CLEN;
  sdt[t] = dtb[dbase + t];
  sdac[t] = dacb[dbase + t];
  __syncthreads();
  float acc[16];
#pragma unroll
  for (int i = 0; i < 16; ++i) acc[i] = 0.f;
  // ---- y_inter: C @ prev ----
  size_t pbase = (((size_t)bk * NCH + z) * NHD + h) * (128 * 64);
  for (int nt = 0; nt < 4; ++nt) {
    for (int e = t; e < 64 * 32; e += 256) {
      int ss = e >> 5, nn = e & 31;
      int pc = pixof(k, z * CLEN + si_t * 64 + ss);
      sC[ss * 33 + nn] = convo[((size_t)(b * LQ + pc)) * CCH + (DSSM + DST) + nt * 32 + nn];
    }
    for (int e = t; e < 32 * 64; e += 256) sP[e] = prevb[pbase + (size_t)nt * 2048 + e];
    __syncthreads();
    for (int nn = 0; nn < 32; ++nn) {
      float pv = sP[nn * 64 + p];
#pragma unroll
      for (int i = 0; i < 16; ++i) acc[i] += sC[(qr * 16 + i) * 33 + nn] * pv;
    }
    __syncthreads();
  }
#pragma unroll
  for (int i = 0; i < 16; ++i) acc[i] *= expf(sdac[si_t * 64 + qr * 16 + i]);
  // ---- y_intra ----
  float ref = sdac[si_t * 64];
  float rs[16];
#pragma unroll
  for (int i = 0; i < 16; ++i) rs[i] = expf(sdac[si_t * 64 + qr * 16 + i] - ref);
  for (int SJ = 0; SJ <= si_t; ++SJ) {
    int pi = si_t * (si_t + 1) / 2 + SJ;
    size_t cbase = ((size_t)(bk * NCH + z) * 10 + pi) * 4096;
    for (int e = t; e < 4096; e += 256) sCB[e] = cbuf[cbase + e];
    bool diag = (SJ == si_t);
    for (int e = t; e < 4096; e += 256) {
      int ss = e >> 6, pp = e & 63;
      int sg = SJ * 64 + ss;
      int px = pixof(k, z * CLEN + sg);
      float xv = convo[((size_t)(b * LQ + px)) * CCH + h * 64 + pp];
      float f = diag ? sdt[sg] : sdt[sg] * expf(ref - sdac[sg]);
      sXW[e] = xv * f;
    }
    __syncthreads();
    if (diag) {
#pragma unroll
      for (int i = 0; i < 16; ++i) {
        int sl = qr * 16 + i;
        float da_i = sdac[si_t * 64 + sl];
        float sum = 0.f;
        for (int ss = 0; ss <= sl; ++ss)
          sum += sCB[sl * 64 + ss] * expf(da_i - sdac[si_t * 64 + ss]) * sXW[ss * 64 + p];
        acc[i] += sum;
      }
    } else {
#pragma unroll
      for (int i = 0; i < 16; ++i) {
        int sl = qr * 16 + i;
        float sum = 0.f;
        for (int ss = 0; ss < 64; ++ss) sum += sCB[sl * 64 + ss] * sXW[ss * 64 + p];
        acc[i] += rs[i] * sum;
      }
    }
    __syncthreads();
  }
  // ---- + D*x, accumulate into combined image ----
  float dsv = Ds[k * NHD + h];
#pragma unroll
  for (int i = 0; i < 16; ++i) {
    int sl = qr * 16 + i;
    int tg = z * CLEN + si_t * 64 + sl;
    int px = pixof(k, tg);
    float xv = convo[((size_t)(b * LQ + px)) * CCH + h * 64 + p];
    atomicAdd(&outpre[((size_t)(b * LQ + px)) * DSSM + h * 64 + p], acc[i] + dsv * xv);
  }
}

// ---- 8. gated RMSNorm + out projection ----
__global__ void k_final(const float* __restrict__ outpre, const float* __restrict__ zbuf,
                        const float* __restrict__ norm_w, const float* __restrict__ Wout,
                        float* __restrict__ out) {
  __shared__ float sg[DSSM];
  __shared__ float sred[256];
  int m = blockIdx.x;
  int t = threadIdx.x;
  float lsum = 0.f;
  for (int c = t; c < DSSM; c += 256) {
    float g = outpre[(size_t)m * DSSM + c] * siluf(zbuf[(size_t)m * DSSM + c]);
    sg[c] = g;
    lsum += g * g;
  }
  sred[t] = lsum;
  __syncthreads();
  for (int off = 128; off > 0; off >>= 1) {
    if (t < off) sred[t] += sred[t + off];
    __syncthreads();
  }
  float rstd = rsqrtf(sred[0] / DSSM + 1e-5f);
  __syncthreads();
  for (int c = t; c < DSSM; c += 256) sg[c] = sg[c] * rstd * norm_w[c];
  __syncthreads();
  if (t < DM) {
    float a = 0.f;
    for (int r = 0; r < DSSM; ++r) a += sg[r] * Wout[r * DM + t];
    out[(size_t)m * DM + t] = a;
  }
}

extern "C" void kernel_launch(void* const* d_in, const int* in_sizes, int n_in,
                              void* d_out, int out_size, void* d_ws, size_t ws_size,
                              hipStream_t stream) {
  const float* u = (const float*)d_in[0];
  const float* W_in = (const float*)d_in[1];
  const float* conv_w = (const float*)d_in[2];
  const float* conv_b = (const float*)d_in[3];
  const float* dt_bias = (const float*)d_in[4];
  const float* A_logs = (const float*)d_in[5];
  const float* Ds = (const float*)d_in[6];
  const float* norm_w = (const float*)d_in[7];
  const float* W_out = (const float*)d_in[8];
  float* out = (float*)d_out;

  float* ws = (float*)d_ws;
  size_t off = 0;
  float* zbuf = ws + off; off += (size_t)BQ * LQ * DSSM;                 // 6.29M
  float* xbc  = ws + off; off += (size_t)BQ * LQ * CCH;                  // 10.58M
  float* convo = ws + off; off += (size_t)BQ * LQ * CCH;                 // 10.58M
  float* dtb  = ws + off; off += (size_t)BQ * KDIR * NCH * NHD * CLEN;   // 0.39M
  float* dacb = ws + off; off += (size_t)BQ * KDIR * NCH * NHD * CLEN;   // 0.39M
  float* states = ws + off; off += (size_t)BQ * KDIR * NCH * NHD * 128 * 64; // 12.58M
  float* outpre = ws + off; off += (size_t)BQ * LQ * DSSM;               // 6.29M
  float* cbuf = xbc;  // alias: xbc dead after conv; CB needs 10.49M <= 10.58M

  hipMemsetAsync(outpre, 0, (size_t)BQ * LQ * DSSM * sizeof(float), stream);

  k_inproj<<<BQ * LQ / 8, 256, 0, stream>>>(u, W_in, zbuf, xbc);
  k_conv<<<BQ * LQ, 256, 0, stream>>>(xbc, conv_w, conv_b, convo);
  k_prep<<<dim3(NCH, KDIR, BQ), 256, 0, stream>>>(convo, dt_bias, A_logs, dtb, dacb);
  k_cb<<<dim3(10, NCH, BQ * KDIR), 256, 0, stream>>>(convo, cbuf);
  k_states<<<dim3(NHD, NCH, BQ * KDIR), 256, 0, stream>>>(convo, dtb, dacb, states);
  k_scan<<<dim3(NHD, KDIR, BQ), 256, 0, stream>>>(states, dacb);
  k_y<<<dim3(4 * NHD, NCH, BQ * KDIR), 256, 0, stream>>>(convo, dtb, dacb, cbuf, states, Ds, outpre);
  k_final<<<BQ * LQ, 256, 0, stream>>>(outpre, zbuf, norm_w, W_out, out);
}

// Round 4
// 1861.381 us; speedup vs baseline: 1.3015x; 1.3015x over previous
//
#include <hip/hip_runtime.h>
#include <hip/hip_fp16.h>
#include <math.h>

#define BQ 4
#define LQ 4096
#define DM 192
#define DIP 1030
#define DSSM 384
#define DST 128
#define CCH 646
#define CH640 640
#define NHD 6
#define KDIR 4
#define NCH 16
#define CLEN 256

__device__ __forceinline__ int pixof(int k, int t) {
  switch (k) {
    case 0: return t;
    case 1: return ((t & 63) << 6) | (t >> 6);
    case 2: return 4095 - t;
    default: { int tp = 4095 - t; return ((tp & 63) << 6) | (tp >> 6); }
  }
}

__device__ __forceinline__ float softplusf(float x) {
  return (x > 20.f) ? x : log1pf(expf(x));
}
__device__ __forceinline__ float siluf(float x) {
  return x / (1.f + __expf(-x));
}

// ---- 1. in_proj GEMM: (B*L,192) @ (192,1030) -> z fp16 (384) | xbc fp32 (646) ----
__global__ void k_inproj(const float* __restrict__ u, const float* __restrict__ W,
                         __half* __restrict__ zh, float* __restrict__ xbc) {
  __shared__ float s_u[8 * DM];
  int m0 = blockIdx.x * 8;
  int t = threadIdx.x;
  for (int e = t; e < 8 * DM; e += 256) s_u[e] = u[(size_t)m0 * DM + e];
  __syncthreads();
  for (int n = t; n < DIP; n += 256) {
    float acc[8];
#pragma unroll
    for (int r = 0; r < 8; ++r) acc[r] = 0.f;
    for (int kk = 0; kk < DM; ++kk) {
      float wv = W[(size_t)kk * DIP + n];
#pragma unroll
      for (int r = 0; r < 8; ++r) acc[r] += s_u[r * DM + kk] * wv;
    }
    if (n < DSSM) {
#pragma unroll
      for (int r = 0; r < 8; ++r) zh[(size_t)(m0 + r) * DSSM + n] = (__half)acc[r];
    } else {
#pragma unroll
      for (int r = 0; r < 8; ++r) xbc[(size_t)(m0 + r) * CCH + (n - DSSM)] = acc[r];
    }
  }
}

// ---- 2. depthwise 3x3 conv + bias + SiLU: out fp16 (x|B|C 640ch) + fp32 dtraw (6ch) ----
__global__ void k_conv(const float* __restrict__ xbc, const float* __restrict__ cw,
                       const float* __restrict__ cb, __half* __restrict__ convh,
                       float* __restrict__ dtraw) {
  int pid = blockIdx.x;  // b*4096 + p
  int b = pid >> 12, p = pid & 4095;
  int y = p >> 6, x = p & 63;
  int t = threadIdx.x;
  const float* base = xbc + (size_t)b * LQ * CCH;
  for (int c = t; c < CCH; c += 256) {
    float s = 0.f;
#pragma unroll
    for (int ky = 0; ky < 3; ++ky) {
      int yy = y + ky - 1;
      if (yy < 0 || yy > 63) continue;
#pragma unroll
      for (int kx = 0; kx < 3; ++kx) {
        int xx = x + kx - 1;
        if (xx < 0 || xx > 63) continue;
        s += base[(size_t)(yy * 64 + xx) * CCH + c] * cw[c * 9 + ky * 3 + kx];
      }
    }
    float v = siluf(s + cb[c]);
    if (c < CH640) convh[(size_t)pid * CH640 + c] = (__half)v;
    else dtraw[(size_t)pid * NHD + (c - CH640)] = v;
  }
}

// ---- 3. dt softplus + per-chunk cumsum of dA (fp32 path) ----
__global__ void k_prep(const float* __restrict__ dtraw, const float* __restrict__ dt_bias,
                       const float* __restrict__ A_logs,
                       float* __restrict__ dtb, float* __restrict__ dacb) {
  __shared__ float sb[CLEN];
  int z = blockIdx.x, k = blockIdx.y, b = blockIdx.z;
  int s = threadIdx.x;
  int pixel = pixof(k, z * CLEN + s);
  const float* row = dtraw + ((size_t)(b * LQ + pixel)) * NHD;
  float raw[NHD];
#pragma unroll
  for (int h = 0; h < NHD; ++h) raw[h] = row[h];
  size_t base = (((size_t)(b * KDIR + k) * NCH + z) * NHD) * CLEN;
  for (int h = 0; h < NHD; ++h) {
    float dtv = softplusf(raw[h] + dt_bias[k * NHD + h]);
    float dA = dtv * (-expf(A_logs[k * NHD + h]));
    sb[s] = dA;
    __syncthreads();
    for (int off = 1; off < CLEN; off <<= 1) {
      float v = (s >= off) ? sb[s - off] : 0.f;
      __syncthreads();
      sb[s] += v;
      __syncthreads();
    }
    dtb[base + (size_t)h * CLEN + s] = dtv;
    dacb[base + (size_t)h * CLEN + s] = sb[s];
    __syncthreads();
  }
}

// ---- 4. CB = C @ B^T, lower-triangle 64x64 tiles, fp16 out ----
__global__ void k_cb(const __half* __restrict__ convh, __half* __restrict__ cbuf) {
  __shared__ float sC[64 * 33];
  __shared__ float sB[64 * 33];
  int pi = blockIdx.x;  // 0..9 tile pair
  int z = blockIdx.y;
  int bk = blockIdx.z;  // b*4 + k
  int b = bk >> 2, k = bk & 3;
  int SI = 0;
  while ((SI + 1) * (SI + 2) / 2 <= pi) ++SI;
  int SJ = pi - SI * (SI + 1) / 2;
  int t = threadIdx.x;
  int sj = t & 63;
  int g = t >> 6;
  float acc[16];
#pragma unroll
  for (int i = 0; i < 16; ++i) acc[i] = 0.f;
  for (int nt = 0; nt < 4; ++nt) {
    for (int e = t; e < 64 * 32; e += 256) {
      int ss = e >> 5, nn = e & 31;
      int pc = pixof(k, z * CLEN + SI * 64 + ss);
      sC[ss * 33 + nn] = (float)convh[((size_t)(b * LQ + pc)) * CH640 + (DSSM + DST) + nt * 32 + nn];
      int pb = pixof(k, z * CLEN + SJ * 64 + ss);
      sB[ss * 33 + nn] = (float)convh[((size_t)(b * LQ + pb)) * CH640 + DSSM + nt * 32 + nn];
    }
    __syncthreads();
    for (int nn = 0; nn < 32; ++nn) {
      float bv = sB[sj * 33 + nn];
#pragma unroll
      for (int i = 0; i < 16; ++i) acc[i] += sC[(g * 16 + i) * 33 + nn] * bv;
    }
    __syncthreads();
  }
  size_t base = ((size_t)(bk * NCH + z) * 10 + pi) * 4096;
#pragma unroll
  for (int i = 0; i < 16; ++i) cbuf[base + (g * 16 + i) * 64 + sj] = (__half)acc[i];
}

// ---- 5. chunk states ----
__global__ void k_states(const __half* __restrict__ convh, const float* __restrict__ dtb,
                         const float* __restrict__ dacb, float* __restrict__ states) {
  __shared__ float sB[64 * 128];
  __shared__ float sX[64 * 64];
  __shared__ float sdt[CLEN];
  __shared__ float sdac[CLEN];
  int h = blockIdx.x, z = blockIdx.y, bk = blockIdx.z;
  int b = bk >> 2, k = bk & 3;
  int t = threadIdx.x;
  size_t dbase = (((size_t)bk * NCH + z) * NHD + h) * CLEN;
  sdt[t] = dtb[dbase + t];
  sdac[t] = dacb[dbase + t];
  __syncthreads();
  float dac_last = sdac[CLEN - 1];
  int p = t & 63;
  int nb = (t >> 6) * 32;
  float acc[32];
#pragma unroll
  for (int j = 0; j < 32; ++j) acc[j] = 0.f;
  for (int st = 0; st < 4; ++st) {
    for (int e = t; e < 64 * 128; e += 256) {
      int ss = e >> 7, nn = e & 127;
      int pp = pixof(k, z * CLEN + st * 64 + ss);
      sB[e] = (float)convh[((size_t)(b * LQ + pp)) * CH640 + DSSM + nn];
    }
    for (int e = t; e < 64 * 64; e += 256) {
      int ss = e >> 6, pp2 = e & 63;
      int sg = st * 64 + ss;
      int px = pixof(k, z * CLEN + sg);
      float xv = (float)convh[((size_t)(b * LQ + px)) * CH640 + h * 64 + pp2];
      sX[e] = xv * sdt[sg] * __expf(dac_last - sdac[sg]);
    }
    __syncthreads();
    for (int ss = 0; ss < 64; ++ss) {
      float xv = sX[ss * 64 + p];
#pragma unroll
      for (int j = 0; j < 32; ++j) acc[j] += sB[ss * 128 + nb + j] * xv;
    }
    __syncthreads();
  }
  size_t sbase = (((size_t)bk * NCH + z) * NHD + h) * (128 * 64);
#pragma unroll
  for (int j = 0; j < 32; ++j) states[sbase + (size_t)(nb + j) * 64 + p] = acc[j];
}

// ---- 6. inter-chunk scan (in place) ----
__global__ void k_scan(float* __restrict__ states, const float* __restrict__ dacb) {
  int h = blockIdx.x, k = blockIdx.y, b = blockIdx.z;
  int bk = b * KDIR + k;
  int t = threadIdx.x;
  float carry[32];
#pragma unroll
  for (int j = 0; j < 32; ++j) carry[j] = 0.f;
  for (int z = 0; z < NCH; ++z) {
    float cd = __expf(dacb[(((size_t)bk * NCH + z) * NHD + h) * CLEN + (CLEN - 1)]);
    size_t sbase = (((size_t)bk * NCH + z) * NHD + h) * (128 * 64);
#pragma unroll
    for (int j = 0; j < 32; ++j) {
      size_t idx = sbase + (size_t)j * 256 + t;
      float sv = states[idx];
      states[idx] = carry[j];
      carry[j] = carry[j] * cd + sv;
    }
  }
}

// ---- 7. y = y_inter + y_intra + D*x -> ybuf (per-direction, sequence-ordered, fp16) ----
__global__ void k_y(const __half* __restrict__ convh, const float* __restrict__ dtb,
                    const float* __restrict__ dacb, const __half* __restrict__ cbuf,
                    const float* __restrict__ prevb, const float* __restrict__ Ds,
                    __half* __restrict__ ybuf) {
  __shared__ float sdt[CLEN];
  __shared__ float sdac[CLEN];
  __shared__ float sFac[CLEN];
  __shared__ float sC[64 * 33];
  __shared__ float sP[32 * 64];
  __shared__ float sCB[64 * 64];
  __shared__ float sXW[64 * 64];
  // 1D grid 6144 with XCD-chunked swizzle: 24 blocks of one (bk,z) group stay on one XCD
  int wg = blockIdx.x;
  int xid = (wg & 7) * 768 + (wg >> 3);
  int grp = xid / 24, i24 = xid % 24;
  int h = i24 >> 2, si_t = i24 & 3;
  int bk = grp >> 4, z = grp & 15;
  int b = bk >> 2, k = bk & 3;
  int t = threadIdx.x;
  int p = t & 63;
  int qr = t >> 6;
  size_t dbase = (((size_t)bk * NCH + z) * NHD + h) * CLEN;
  sdt[t] = dtb[dbase + t];
  sdac[t] = dacb[dbase + t];
  __syncthreads();
  float ref = sdac[si_t * 64];
  // decay factor from position t to tile-start row; only used for t < si_t*64 (arg<=0)
  sFac[t] = __expf(ref - sdac[t]);
  float acc[16];
#pragma unroll
  for (int i = 0; i < 16; ++i) acc[i] = 0.f;
  // ---- y_inter: C @ prev ----
  size_t pbase = (((size_t)bk * NCH + z) * NHD + h) * (128 * 64);
  for (int nt = 0; nt < 4; ++nt) {
    for (int e = t; e < 64 * 32; e += 256) {
      int ss = e >> 5, nn = e & 31;
      int pc = pixof(k, z * CLEN + si_t * 64 + ss);
      sC[ss * 33 + nn] = (float)convh[((size_t)(b * LQ + pc)) * CH640 + (DSSM + DST) + nt * 32 + nn];
    }
    for (int e = t; e < 32 * 64; e += 256) sP[e] = prevb[pbase + (size_t)nt * 2048 + e];
    __syncthreads();  // first pass also covers sFac
    for (int nn = 0; nn < 32; ++nn) {
      float pv = sP[nn * 64 + p];
#pragma unroll
      for (int i = 0; i < 16; ++i) acc[i] += sC[(qr * 16 + i) * 33 + nn] * pv;
    }
    __syncthreads();
  }
#pragma unroll
  for (int i = 0; i < 16; ++i) acc[i] *= __expf(sdac[si_t * 64 + qr * 16 + i]);
  // ---- y_intra ----
  float rs[16];
#pragma unroll
  for (int i = 0; i < 16; ++i) rs[i] = __expf(sdac[si_t * 64 + qr * 16 + i] - ref);
  for (int SJ = 0; SJ <= si_t; ++SJ) {
    int pi = si_t * (si_t + 1) / 2 + SJ;
    size_t cbase = ((size_t)(bk * NCH + z) * 10 + pi) * 4096;
    bool diag = (SJ == si_t);
    for (int e = t; e < 4096; e += 256) {
      float cv = (float)cbuf[cbase + e];
      if (diag) {
        int sl = e >> 6, ss = e & 63;
        cv = (ss <= sl) ? cv * __expf(sdac[si_t * 64 + sl] - sdac[si_t * 64 + ss]) : 0.f;
      }
      sCB[e] = cv;
    }
    for (int e = t; e < 4096; e += 256) {
      int ss = e >> 6, pp = e & 63;
      int sg = SJ * 64 + ss;
      int px = pixof(k, z * CLEN + sg);
      float xv = (float)convh[((size_t)(b * LQ + px)) * CH640 + h * 64 + pp];
      sXW[e] = diag ? xv * sdt[sg] : xv * sdt[sg] * sFac[sg];
    }
    __syncthreads();
    if (diag) {
#pragma unroll
      for (int i = 0; i < 16; ++i) {
        int sl = qr * 16 + i;
        float sum = 0.f;
        for (int ss = 0; ss < 64; ++ss) sum += sCB[sl * 64 + ss] * sXW[ss * 64 + p];
        acc[i] += sum;  // mask folded into sCB zeros
      }
    } else {
#pragma unroll
      for (int i = 0; i < 16; ++i) {
        int sl = qr * 16 + i;
        float sum = 0.f;
        for (int ss = 0; ss < 64; ++ss) sum += sCB[sl * 64 + ss] * sXW[ss * 64 + p];
        acc[i] += rs[i] * sum;
      }
    }
    __syncthreads();
  }
  // ---- + D*x, coalesced per-direction write (no atomics) ----
  float dsv = Ds[k * NHD + h];
#pragma unroll
  for (int i = 0; i < 16; ++i) {
    int sl = qr * 16 + i;
    int tg = z * CLEN + si_t * 64 + sl;
    int px = pixof(k, tg);
    float xv = (float)convh[((size_t)(b * LQ + px)) * CH640 + h * 64 + p];
    ybuf[((size_t)bk * LQ + tg) * DSSM + h * 64 + p] = (__half)(acc[i] + dsv * xv);
  }
}

// ---- 8. gather 4 directions + gated RMSNorm + out projection (8 px / block) ----
__global__ void k_final(const __half* __restrict__ yb, const __half* __restrict__ zh,
                        const float* __restrict__ norm_w, const float* __restrict__ Wout,
                        float* __restrict__ out) {
  __shared__ float sg[8 * DSSM];
  __shared__ float srstd[8];
  int m0 = blockIdx.x * 8;
  int t = threadIdx.x;
  for (int rr = 0; rr < 8; ++rr) {
    int m = m0 + rr, b = m >> 12, px = m & 4095;
    int tr = ((px & 63) << 6) | (px >> 6);
    int t0 = px, t1 = tr, t2 = 4095 - px, t3 = 4095 - tr;
    size_t b4 = (size_t)b * 4;
    for (int c = t; c < DSSM; c += 256) {
      float yv = (float)yb[((b4 + 0) * LQ + t0) * DSSM + c] +
                 (float)yb[((b4 + 1) * LQ + t1) * DSSM + c] +
                 (float)yb[((b4 + 2) * LQ + t2) * DSSM + c] +
                 (float)yb[((b4 + 3) * LQ + t3) * DSSM + c];
      float zv = (float)zh[(size_t)m * DSSM + c];
      sg[rr * DSSM + c] = yv * (zv / (1.f + __expf(-zv)));
    }
  }
  __syncthreads();
  {
    int r = t >> 5, j = t & 31;
    float s = 0.f;
    for (int c = j; c < DSSM; c += 32) { float g = sg[r * DSSM + c]; s += g * g; }
    s += __shfl_xor(s, 16, 32);
    s += __shfl_xor(s, 8, 32);
    s += __shfl_xor(s, 4, 32);
    s += __shfl_xor(s, 2, 32);
    s += __shfl_xor(s, 1, 32);
    if (j == 0) srstd[r] = rsqrtf(s / (float)DSSM + 1e-5f);
  }
  __syncthreads();
  for (int rr = 0; rr < 8; ++rr)
    for (int c = t; c < DSSM; c += 256) sg[rr * DSSM + c] *= srstd[rr] * norm_w[c];
  __syncthreads();
  if (t < DM) {
    float a[8];
#pragma unroll
    for (int rr = 0; rr < 8; ++rr) a[rr] = 0.f;
    for (int c = 0; c < DSSM; ++c) {
      float wv = Wout[(size_t)c * DM + t];
#pragma unroll
      for (int rr = 0; rr < 8; ++rr) a[rr] += sg[rr * DSSM + c] * wv;
    }
#pragma unroll
    for (int rr = 0; rr < 8; ++rr) out[(size_t)(m0 + rr) * DM + t] = a[rr];
  }
}

extern "C" void kernel_launch(void* const* d_in, const int* in_sizes, int n_in,
                              void* d_out, int out_size, void* d_ws, size_t ws_size,
                              hipStream_t stream) {
  const float* u = (const float*)d_in[0];
  const float* W_in = (const float*)d_in[1];
  const float* conv_w = (const float*)d_in[2];
  const float* conv_b = (const float*)d_in[3];
  const float* dt_bias = (const float*)d_in[4];
  const float* A_logs = (const float*)d_in[5];
  const float* Ds = (const float*)d_in[6];
  const float* norm_w = (const float*)d_in[7];
  const float* W_out = (const float*)d_in[8];
  float* out = (float*)d_out;

  float* ws = (float*)d_ws;
  size_t off = 0;
  __half* zh = (__half*)(ws + off); off += (size_t)BQ * LQ * DSSM / 2;          // 3.146M fl
  float* xbc = ws + off; off += (size_t)BQ * LQ * CCH;                           // 10.584M
  __half* convh = (__half*)(ws + off); off += (size_t)BQ * LQ * CH640 / 2;      // 5.243M
  float* dtraw = ws + off; off += (size_t)BQ * LQ * NHD;                         // 0.098M
  float* dtb = ws + off; off += (size_t)BQ * KDIR * NCH * NHD * CLEN;            // 0.393M
  float* dacb = ws + off; off += (size_t)BQ * KDIR * NCH * NHD * CLEN;           // 0.393M
  float* states = ws + off; off += (size_t)BQ * KDIR * NCH * NHD * 128 * 64;     // 12.583M
  __half* ybuf = (__half*)(ws + off); off += (size_t)BQ * KDIR * LQ * DSSM / 2;  // 12.583M
  __half* cbuf = (__half*)xbc;  // alias: xbc dead after conv; 10.49M halves <= 10.58M floats

  k_inproj<<<BQ * LQ / 8, 256, 0, stream>>>(u, W_in, zh, xbc);
  k_conv<<<BQ * LQ, 256, 0, stream>>>(xbc, conv_w, conv_b, convh, dtraw);
  k_prep<<<dim3(NCH, KDIR, BQ), 256, 0, stream>>>(dtraw, dt_bias, A_logs, dtb, dacb);
  k_cb<<<dim3(10, NCH, BQ * KDIR), 256, 0, stream>>>(convh, cbuf);
  k_states<<<dim3(NHD, NCH, BQ * KDIR), 256, 0, stream>>>(convh, dtb, dacb, states);
  k_scan<<<dim3(NHD, KDIR, BQ), 256, 0, stream>>>(states, dacb);
  k_y<<<KDIR * NHD * 4 * NCH * BQ, 256, 0, stream>>>(convh, dtb, dacb, cbuf, states, Ds, ybuf);
  k_final<<<BQ * LQ / 8, 256, 0, stream>>>(ybuf, zh, norm_w, W_out, out);
}

// Round 5
// 805.448 us; speedup vs baseline: 3.0078x; 2.3110x over previous
//
#include <hip/hip_runtime.h>
#include <hip/hip_fp16.h>
#include <math.h>

#define BQ 4
#define LQ 4096
#define DM 192
#define DIP 1030
#define DSSM 384
#define DST 128
#define CCH 646
#define CH640 640
#define NHD 6
#define KDIR 4
#define NCH 16
#define CLEN 256

using half8 = __attribute__((ext_vector_type(8))) _Float16;
using half4 = __attribute__((ext_vector_type(4))) _Float16;
using f32x4 = __attribute__((ext_vector_type(4))) float;

__device__ __forceinline__ int pixof(int k, int t) {
  switch (k) {
    case 0: return t;
    case 1: return ((t & 63) << 6) | (t >> 6);
    case 2: return 4095 - t;
    default: { int tp = 4095 - t; return ((tp & 63) << 6) | (tp >> 6); }
  }
}

__device__ __forceinline__ float softplusf(float x) {
  return (x > 20.f) ? x : log1pf(expf(x));
}
__device__ __forceinline__ float siluf(float x) {
  return x / (1.f + __expf(-x));
}

// ---- 1. in_proj GEMM: (B*L,192) @ (192,1030) -> z fp16 (384) | xbc fp32 (646) ----
__global__ void k_inproj(const float* __restrict__ u, const float* __restrict__ W,
                         __half* __restrict__ zh, float* __restrict__ xbc) {
  __shared__ float s_u[8 * DM];
  int m0 = blockIdx.x * 8;
  int t = threadIdx.x;
  for (int e = t; e < 8 * DM; e += 256) s_u[e] = u[(size_t)m0 * DM + e];
  __syncthreads();
  for (int n = t; n < DIP; n += 256) {
    float acc[8];
#pragma unroll
    for (int r = 0; r < 8; ++r) acc[r] = 0.f;
    for (int kk = 0; kk < DM; ++kk) {
      float wv = W[(size_t)kk * DIP + n];
#pragma unroll
      for (int r = 0; r < 8; ++r) acc[r] += s_u[r * DM + kk] * wv;
    }
    if (n < DSSM) {
#pragma unroll
      for (int r = 0; r < 8; ++r) zh[(size_t)(m0 + r) * DSSM + n] = (__half)acc[r];
    } else {
#pragma unroll
      for (int r = 0; r < 8; ++r) xbc[(size_t)(m0 + r) * CCH + (n - DSSM)] = acc[r];
    }
  }
}

// ---- 2. depthwise 3x3 conv + bias + SiLU: out fp16 (x|B|C 640ch) + fp32 dtraw (6ch) ----
__global__ void k_conv(const float* __restrict__ xbc, const float* __restrict__ cw,
                       const float* __restrict__ cb, __half* __restrict__ convh,
                       float* __restrict__ dtraw) {
  int pid = blockIdx.x;  // b*4096 + p
  int b = pid >> 12, p = pid & 4095;
  int y = p >> 6, x = p & 63;
  int t = threadIdx.x;
  const float* base = xbc + (size_t)b * LQ * CCH;
  for (int c = t; c < CCH; c += 256) {
    float s = 0.f;
#pragma unroll
    for (int ky = 0; ky < 3; ++ky) {
      int yy = y + ky - 1;
      if (yy < 0 || yy > 63) continue;
#pragma unroll
      for (int kx = 0; kx < 3; ++kx) {
        int xx = x + kx - 1;
        if (xx < 0 || xx > 63) continue;
        s += base[(size_t)(yy * 64 + xx) * CCH + c] * cw[c * 9 + ky * 3 + kx];
      }
    }
    float v = siluf(s + cb[c]);
    if (c < CH640) convh[(size_t)pid * CH640 + c] = (__half)v;
    else dtraw[(size_t)pid * NHD + (c - CH640)] = v;
  }
}

// ---- 3. dt softplus + per-chunk cumsum of dA (fp32 path) ----
__global__ void k_prep(const float* __restrict__ dtraw, const float* __restrict__ dt_bias,
                       const float* __restrict__ A_logs,
                       float* __restrict__ dtb, float* __restrict__ dacb) {
  __shared__ float sb[CLEN];
  int z = blockIdx.x, k = blockIdx.y, b = blockIdx.z;
  int s = threadIdx.x;
  int pixel = pixof(k, z * CLEN + s);
  const float* row = dtraw + ((size_t)(b * LQ + pixel)) * NHD;
  float raw[NHD];
#pragma unroll
  for (int h = 0; h < NHD; ++h) raw[h] = row[h];
  size_t base = (((size_t)(b * KDIR + k) * NCH + z) * NHD) * CLEN;
  for (int h = 0; h < NHD; ++h) {
    float dtv = softplusf(raw[h] + dt_bias[k * NHD + h]);
    float dA = dtv * (-expf(A_logs[k * NHD + h]));
    sb[s] = dA;
    __syncthreads();
    for (int off = 1; off < CLEN; off <<= 1) {
      float v = (s >= off) ? sb[s - off] : 0.f;
      __syncthreads();
      sb[s] += v;
      __syncthreads();
    }
    dtb[base + (size_t)h * CLEN + s] = dtv;
    dacb[base + (size_t)h * CLEN + s] = sb[s];
    __syncthreads();
  }
}

// ---- 4. CB = C @ B^T via fp16 MFMA, lower-triangle 64x64 tiles, fp16 out ----
__global__ __launch_bounds__(256, 4) void k_cb(const _Float16* __restrict__ convh,
                                               _Float16* __restrict__ cbuf) {
  __shared__ __align__(16) char smem[34816];
  _Float16* sCt = (_Float16*)smem;             // [64][136]
  _Float16* sBt = (_Float16*)(smem + 17408);   // [64][136]
  int pi = blockIdx.x, z = blockIdx.y, bk = blockIdx.z;
  int b = bk >> 2, kd = bk & 3;
  int SI = 0;
  while ((SI + 1) * (SI + 2) / 2 <= pi) ++SI;
  int SJ = pi - SI * (SI + 1) / 2;
  int t = threadIdx.x, lane = t & 63, w = t >> 6;
  int acol = lane & 15, koff = (lane >> 4) * 8;
  int R = w * 16, arow = R + acol, rbase = R + (lane >> 4) * 4;
  const _Float16* convb = convh + (size_t)b * LQ * CH640;
  for (int i = 0; i < 4; ++i) {
    int c = t + i * 256;
    int row = c >> 4, seg = c & 15;
    int pc = pixof(kd, z * CLEN + SI * 64 + row);
    *(half8*)&sCt[row * 136 + seg * 8] =
        *(const half8*)&convb[(size_t)pc * CH640 + (DSSM + DST) + seg * 8];
    int pbx = pixof(kd, z * CLEN + SJ * 64 + row);
    *(half8*)&sBt[row * 136 + seg * 8] =
        *(const half8*)&convb[(size_t)pbx * CH640 + DSSM + seg * 8];
  }
  __syncthreads();
  f32x4 zz = {0.f, 0.f, 0.f, 0.f};
  f32x4 acc[4] = {zz, zz, zz, zz};
  for (int ks = 0; ks < 4; ++ks) {
    half8 a = *(const half8*)&sCt[arow * 136 + ks * 32 + koff];
#pragma unroll
    for (int cg = 0; cg < 4; ++cg) {
      half8 bf = *(const half8*)&sBt[(cg * 16 + acol) * 136 + ks * 32 + koff];
      acc[cg] = __builtin_amdgcn_mfma_f32_16x16x32_f16(a, bf, acc[cg], 0, 0, 0);
    }
  }
  size_t base = ((size_t)(bk * NCH + z) * 10 + pi) * 4096;
#pragma unroll
  for (int cg = 0; cg < 4; ++cg)
#pragma unroll
    for (int r = 0; r < 4; ++r)
      cbuf[base + (size_t)(rbase + r) * 64 + cg * 16 + acol] = (_Float16)acc[cg][r];
}

// ---- 5. chunk states -> TRANSPOSED statesT[p][n] ----
__global__ void k_states(const _Float16* __restrict__ convh, const float* __restrict__ dtb,
                         const float* __restrict__ dacb, float* __restrict__ statesT) {
  __shared__ float sB[64 * 128];
  __shared__ float sX[64 * 64];
  __shared__ float sdt[CLEN];
  __shared__ float sdac[CLEN];
  int h = blockIdx.x, z = blockIdx.y, bk = blockIdx.z;
  int b = bk >> 2, kd = bk & 3;
  int t = threadIdx.x;
  size_t dbase = (((size_t)bk * NCH + z) * NHD + h) * CLEN;
  sdt[t] = dtb[dbase + t];
  sdac[t] = dacb[dbase + t];
  __syncthreads();
  float dac_last = sdac[CLEN - 1];
  int n = t & 127;
  int pb = (t >> 7) * 32;
  float acc[32];
#pragma unroll
  for (int jp = 0; jp < 32; ++jp) acc[jp] = 0.f;
  for (int st = 0; st < 4; ++st) {
    for (int e = t; e < 64 * 128; e += 256) {
      int ss = e >> 7, nn = e & 127;
      int pp = pixof(kd, z * CLEN + st * 64 + ss);
      sB[e] = (float)convh[((size_t)(b * LQ + pp)) * CH640 + DSSM + nn];
    }
    for (int e = t; e < 64 * 64; e += 256) {
      int ss = e >> 6, pp2 = e & 63;
      int sg = st * 64 + ss;
      int px = pixof(kd, z * CLEN + sg);
      float xvv = (float)convh[((size_t)(b * LQ + px)) * CH640 + h * 64 + pp2];
      sX[e] = xvv * sdt[sg] * __expf(dac_last - sdac[sg]);
    }
    __syncthreads();
    for (int ss = 0; ss < 64; ++ss) {
      float bv = sB[ss * 128 + n];
#pragma unroll
      for (int jp = 0; jp < 32; ++jp) acc[jp] += sX[ss * 64 + pb + jp] * bv;
    }
    __syncthreads();
  }
  size_t sbase = (((size_t)bk * NCH + z) * NHD + h) * (128 * 64);
#pragma unroll
  for (int jp = 0; jp < 32; ++jp) statesT[sbase + (size_t)(pb + jp) * 128 + n] = acc[jp];
}

// ---- 6. inter-chunk scan (in place, layout-agnostic) ----
__global__ void k_scan(float* __restrict__ states, const float* __restrict__ dacb) {
  int h = blockIdx.x, k = blockIdx.y, b = blockIdx.z;
  int bk = b * KDIR + k;
  int t = threadIdx.x;
  float carry[32];
#pragma unroll
  for (int j = 0; j < 32; ++j) carry[j] = 0.f;
  for (int z = 0; z < NCH; ++z) {
    float cd = __expf(dacb[(((size_t)bk * NCH + z) * NHD + h) * CLEN + (CLEN - 1)]);
    size_t sbase = (((size_t)bk * NCH + z) * NHD + h) * (128 * 64);
#pragma unroll
    for (int j = 0; j < 32; ++j) {
      size_t idx = sbase + (size_t)j * 256 + t;
      float sv = states[idx];
      states[idx] = carry[j];
      carry[j] = carry[j] * cd + sv;
    }
  }
}

// ---- 7. y via fp16 MFMA -> ybuf (per-direction, sequence-ordered, fp16) ----
__global__ __launch_bounds__(256, 4) void k_y(
    const _Float16* __restrict__ convh, const float* __restrict__ dtb,
    const float* __restrict__ dacb, const _Float16* __restrict__ cbuf,
    const float* __restrict__ prevT, const float* __restrict__ Ds,
    _Float16* __restrict__ ybuf) {
  __shared__ __align__(16) char smem[34816];
  __shared__ float sdt[CLEN], sdac[CLEN], sFac[CLEN];
  __shared__ float sExpD[64], sRs[64];
  _Float16* sC = (_Float16*)smem;              // phase A: [64][136]
  _Float16* sPrev = (_Float16*)(smem + 17408); // phase A: [64][136]
  _Float16* sA = (_Float16*)smem;              // phase B: [64][72]
  _Float16* sXW = (_Float16*)(smem + 9216);    // phase B: [64][72]

  int wg = blockIdx.x;  // 6144 = 8 XCD * 768
  int xid = (wg & 7) * 768 + (wg >> 3);
  int grp = xid / 24, i24 = xid % 24;
  int h = i24 >> 2, si_t = i24 & 3;
  int bk = grp >> 4, z = grp & 15;
  int b = bk >> 2, kd = bk & 3;
  int t = threadIdx.x;
  int lane = t & 63, w = t >> 6;
  int acol = lane & 15, koff = (lane >> 4) * 8;
  int R = w * 16, arow = R + acol, rbase = R + (lane >> 4) * 4;

  size_t dbase = (((size_t)bk * NCH + z) * NHD + h) * CLEN;
  sdt[t] = dtb[dbase + t];
  sdac[t] = dacb[dbase + t];
  __syncthreads();
  float ref = sdac[si_t * 64];
  sFac[t] = __expf(ref - sdac[t]);
  if (t < 64) {
    float d = sdac[si_t * 64 + t];
    sExpD[t] = __expf(d);
    sRs[t] = __expf(d - ref);
  }
  const _Float16* convb = convh + (size_t)b * LQ * CH640;
  // stage C tile [64 rows][128 n] fp16
  for (int i = 0; i < 4; ++i) {
    int c = t + i * 256;
    int row = c >> 4, seg = c & 15;
    int px = pixof(kd, z * CLEN + si_t * 64 + row);
    *(half8*)&sC[row * 136 + seg * 8] =
        *(const half8*)&convb[(size_t)px * CH640 + (DSSM + DST) + seg * 8];
  }
  // stage prevT fp32 -> fp16 [64 p][128 n]
  const float* pbp = prevT + (((size_t)bk * NCH + z) * NHD + h) * (128 * 64);
  for (int i = 0; i < 8; ++i) {
    int idx = t + i * 256;
    int p = idx >> 5, n0 = (idx & 31) * 4;
    float4 v = *(const float4*)&pbp[(size_t)p * 128 + n0];
    half4 hv;
    hv[0] = (_Float16)v.x; hv[1] = (_Float16)v.y;
    hv[2] = (_Float16)v.z; hv[3] = (_Float16)v.w;
    *(half4*)&sPrev[p * 136 + n0] = hv;
  }
  __syncthreads();
  // ---- y_inter: accE = C @ prev ----
  f32x4 zz = {0.f, 0.f, 0.f, 0.f};
  f32x4 accE[4] = {zz, zz, zz, zz};
  for (int ks = 0; ks < 4; ++ks) {
    half8 a = *(const half8*)&sC[arow * 136 + ks * 32 + koff];
#pragma unroll
    for (int cg = 0; cg < 4; ++cg) {
      half8 bf = *(const half8*)&sPrev[(cg * 16 + acol) * 136 + ks * 32 + koff];
      accE[cg] = __builtin_amdgcn_mfma_f32_16x16x32_f16(a, bf, accE[cg], 0, 0, 0);
    }
  }
  __syncthreads();  // phase A region dead; phase B may overwrite
  // ---- y_intra off-diagonal: accumulate over SJ < si_t ----
  f32x4 accI[4] = {zz, zz, zz, zz};
  for (int SJ = 0; SJ < si_t; ++SJ) {
    for (int i = 0; i < 2; ++i) {
      int c = t + i * 256;
      int ss = c >> 3, pp0 = (c & 7) * 8;
      int sg = SJ * 64 + ss;
      int px = pixof(kd, z * CLEN + sg);
      half8 xv = *(const half8*)&convb[(size_t)px * CH640 + h * 64 + pp0];
      float f = sdt[sg] * sFac[sg];
#pragma unroll
      for (int u = 0; u < 8; ++u)
        sXW[(pp0 + u) * 72 + ss] = (_Float16)((float)xv[u] * f);
    }
    __syncthreads();
    size_t cbase = ((size_t)(bk * NCH + z) * 10 + si_t * (si_t + 1) / 2 + SJ) * 4096;
#pragma unroll
    for (int ks = 0; ks < 2; ++ks) {
      half8 a = *(const half8*)&cbuf[cbase + (size_t)arow * 64 + ks * 32 + koff];
#pragma unroll
      for (int cg = 0; cg < 4; ++cg) {
        half8 bf = *(const half8*)&sXW[(cg * 16 + acol) * 72 + ks * 32 + koff];
        accI[cg] = __builtin_amdgcn_mfma_f32_16x16x32_f16(a, bf, accI[cg], 0, 0, 0);
      }
    }
    __syncthreads();
  }
  // scale off-diag partial by per-row decay rs
  {
    float rsv[4];
#pragma unroll
    for (int r = 0; r < 4; ++r) rsv[r] = sRs[rbase + r];
#pragma unroll
    for (int cg = 0; cg < 4; ++cg)
#pragma unroll
      for (int r = 0; r < 4; ++r) accI[cg][r] *= rsv[r];
  }
  // ---- diagonal tile: decay+mask folded into A' ----
  {
    size_t cbase = ((size_t)(bk * NCH + z) * 10 + si_t * (si_t + 1) / 2 + si_t) * 4096;
    for (int i = 0; i < 16; ++i) {
      int e = t + i * 256;
      int sl = e >> 6, ss = e & 63;
      float cv = 0.f;
      if (ss <= sl)
        cv = (float)cbuf[cbase + e] * __expf(sdac[si_t * 64 + sl] - sdac[si_t * 64 + ss]);
      sA[sl * 72 + ss] = (_Float16)cv;
    }
    for (int i = 0; i < 2; ++i) {
      int c = t + i * 256;
      int ss = c >> 3, pp0 = (c & 7) * 8;
      int sg = si_t * 64 + ss;
      int px = pixof(kd, z * CLEN + sg);
      half8 xv = *(const half8*)&convb[(size_t)px * CH640 + h * 64 + pp0];
      float f = sdt[sg];
#pragma unroll
      for (int u = 0; u < 8; ++u)
        sXW[(pp0 + u) * 72 + ss] = (_Float16)((float)xv[u] * f);
    }
    __syncthreads();
#pragma unroll
    for (int ks = 0; ks < 2; ++ks) {
      half8 a = *(const half8*)&sA[arow * 72 + ks * 32 + koff];
#pragma unroll
      for (int cg = 0; cg < 4; ++cg) {
        half8 bf = *(const half8*)&sXW[(cg * 16 + acol) * 72 + ks * 32 + koff];
        accI[cg] = __builtin_amdgcn_mfma_f32_16x16x32_f16(a, bf, accI[cg], 0, 0, 0);
      }
    }
  }
  // ---- write: y = accI + exp(dac)*accE + D*x ----
  float dsv = Ds[kd * NHD + h];
  float eD[4];
#pragma unroll
  for (int r = 0; r < 4; ++r) eD[r] = sExpD[rbase + r];
#pragma unroll
  for (int cg = 0; cg < 4; ++cg) {
    int col = cg * 16 + acol;
#pragma unroll
    for (int r = 0; r < 4; ++r) {
      int row = rbase + r;
      int tg = z * CLEN + si_t * 64 + row;
      int px = pixof(kd, tg);
      float xv = (float)convb[(size_t)px * CH640 + h * 64 + col];
      float yv = accI[cg][r] + eD[r] * accE[cg][r] + dsv * xv;
      ybuf[((size_t)bk * LQ + tg) * DSSM + h * 64 + col] = (_Float16)yv;
    }
  }
}

// ---- 8. gather 4 directions + gated RMSNorm + out projection (8 px / block) ----
__global__ void k_final(const __half* __restrict__ yb, const __half* __restrict__ zh,
                        const float* __restrict__ norm_w, const float* __restrict__ Wout,
                        float* __restrict__ out) {
  __shared__ float sg[8 * DSSM];
  __shared__ float srstd[8];
  int m0 = blockIdx.x * 8;
  int t = threadIdx.x;
  for (int rr = 0; rr < 8; ++rr) {
    int m = m0 + rr, b = m >> 12, px = m & 4095;
    int tr = ((px & 63) << 6) | (px >> 6);
    int t0 = px, t1 = tr, t2 = 4095 - px, t3 = 4095 - tr;
    size_t b4 = (size_t)b * 4;
    for (int c = t; c < DSSM; c += 256) {
      float yv = (float)yb[((b4 + 0) * LQ + t0) * DSSM + c] +
                 (float)yb[((b4 + 1) * LQ + t1) * DSSM + c] +
                 (float)yb[((b4 + 2) * LQ + t2) * DSSM + c] +
                 (float)yb[((b4 + 3) * LQ + t3) * DSSM + c];
      float zv = (float)zh[(size_t)m * DSSM + c];
      sg[rr * DSSM + c] = yv * (zv / (1.f + __expf(-zv)));
    }
  }
  __syncthreads();
  {
    int r = t >> 5, j = t & 31;
    float s = 0.f;
    for (int c = j; c < DSSM; c += 32) { float g = sg[r * DSSM + c]; s += g * g; }
    s += __shfl_xor(s, 16, 32);
    s += __shfl_xor(s, 8, 32);
    s += __shfl_xor(s, 4, 32);
    s += __shfl_xor(s, 2, 32);
    s += __shfl_xor(s, 1, 32);
    if (j == 0) srstd[r] = rsqrtf(s / (float)DSSM + 1e-5f);
  }
  __syncthreads();
  for (int rr = 0; rr < 8; ++rr)
    for (int c = t; c < DSSM; c += 256) sg[rr * DSSM + c] *= srstd[rr] * norm_w[c];
  __syncthreads();
  if (t < DM) {
    float a[8];
#pragma unroll
    for (int rr = 0; rr < 8; ++rr) a[rr] = 0.f;
    for (int c = 0; c < DSSM; ++c) {
      float wv = Wout[(size_t)c * DM + t];
#pragma unroll
      for (int rr = 0; rr < 8; ++rr) a[rr] += sg[rr * DSSM + c] * wv;
    }
#pragma unroll
    for (int rr = 0; rr < 8; ++rr) out[(size_t)(m0 + rr) * DM + t] = a[rr];
  }
}

extern "C" void kernel_launch(void* const* d_in, const int* in_sizes, int n_in,
                              void* d_out, int out_size, void* d_ws, size_t ws_size,
                              hipStream_t stream) {
  const float* u = (const float*)d_in[0];
  const float* W_in = (const float*)d_in[1];
  const float* conv_w = (const float*)d_in[2];
  const float* conv_b = (const float*)d_in[3];
  const float* dt_bias = (const float*)d_in[4];
  const float* A_logs = (const float*)d_in[5];
  const float* Ds = (const float*)d_in[6];
  const float* norm_w = (const float*)d_in[7];
  const float* W_out = (const float*)d_in[8];
  float* out = (float*)d_out;

  float* ws = (float*)d_ws;
  size_t off = 0;
  __half* zh = (__half*)(ws + off); off += (size_t)BQ * LQ * DSSM / 2;
  float* xbc = ws + off; off += (size_t)BQ * LQ * CCH;
  __half* convh = (__half*)(ws + off); off += (size_t)BQ * LQ * CH640 / 2;
  float* dtraw = ws + off; off += (size_t)BQ * LQ * NHD;
  float* dtb = ws + off; off += (size_t)BQ * KDIR * NCH * NHD * CLEN;
  float* dacb = ws + off; off += (size_t)BQ * KDIR * NCH * NHD * CLEN;
  float* statesT = ws + off; off += (size_t)BQ * KDIR * NCH * NHD * 128 * 64;
  __half* ybuf = (__half*)(ws + off); off += (size_t)BQ * KDIR * LQ * DSSM / 2;
  _Float16* cbuf = (_Float16*)xbc;  // alias: xbc dead after conv

  k_inproj<<<BQ * LQ / 8, 256, 0, stream>>>(u, W_in, zh, xbc);
  k_conv<<<BQ * LQ, 256, 0, stream>>>(xbc, conv_w, conv_b, convh, dtraw);
  k_prep<<<dim3(NCH, KDIR, BQ), 256, 0, stream>>>(dtraw, dt_bias, A_logs, dtb, dacb);
  k_cb<<<dim3(10, NCH, BQ * KDIR), 256, 0, stream>>>((const _Float16*)convh, cbuf);
  k_states<<<dim3(NHD, NCH, BQ * KDIR), 256, 0, stream>>>((const _Float16*)convh, dtb, dacb, statesT);
  k_scan<<<dim3(NHD, KDIR, BQ), 256, 0, stream>>>(statesT, dacb);
  k_y<<<KDIR * NHD * 4 * NCH * BQ, 256, 0, stream>>>((const _Float16*)convh, dtb, dacb,
                                                     (const _Float16*)cbuf, statesT, Ds,
                                                     (_Float16*)ybuf);
  k_final<<<BQ * LQ / 8, 256, 0, stream>>>(ybuf, zh, norm_w, W_out, out);
}

// Round 6
// 662.157 us; speedup vs baseline: 3.6587x; 1.2164x over previous
//
#include <hip/hip_runtime.h>
#include <hip/hip_fp16.h>
#include <math.h>

#define BQ 4
#define LQ 4096
#define DM 192
#define DIP 1030
#define DSSM 384
#define DST 128
#define CCH 646
#define CH640 640
#define NHD 6
#define KDIR 4
#define NCH 16
#define CLEN 256
#define UH_ELEMS (16384 * 192)
#define WT_ELEMS (1152 * 192)

using half8 = __attribute__((ext_vector_type(8))) _Float16;
using half4 = __attribute__((ext_vector_type(4))) _Float16;
using f32x4 = __attribute__((ext_vector_type(4))) float;

// swizzled XW index: conflict-free scatter-write + aligned b128 read
#define XWI(pp, ss) (((pp) << 6) + ((((ss) >> 3) ^ ((pp) >> 3)) << 3) + ((ss) & 7))

__device__ __forceinline__ int pixof(int k, int t) {
  switch (k) {
    case 0: return t;
    case 1: return ((t & 63) << 6) | (t >> 6);
    case 2: return 4095 - t;
    default: { int tp = 4095 - t; return ((tp & 63) << 6) | (tp >> 6); }
  }
}

__device__ __forceinline__ float softplusf(float x) {
  return (x > 20.f) ? x : log1pf(expf(x));
}
__device__ __forceinline__ float siluf(float x) {
  return x / (1.f + __expf(-x));
}

// ---- 0. convert u -> fp16, W_in -> fp16 transposed [1152][192], zero-padded ----
__global__ void k_cvt(const float* __restrict__ u, const float* __restrict__ W,
                      _Float16* __restrict__ uh, _Float16* __restrict__ whT) {
  int idx = blockIdx.x * 256 + threadIdx.x;
  if (idx < UH_ELEMS) uh[idx] = (_Float16)u[idx];
  int widx = idx - UH_ELEMS;
  if (widx >= 0 && widx < WT_ELEMS) {
    int n = widx / 192, kk = widx - n * 192;
    whT[widx] = (n < DIP) ? (_Float16)W[(size_t)kk * DIP + n] : (_Float16)0.f;
  }
}

// ---- 1. in_proj via fp16 MFMA: (16384,192)@(192,1152) -> zh | xbch | xdt32 ----
__global__ __launch_bounds__(256) void k_inproj(
    const _Float16* __restrict__ uh, const _Float16* __restrict__ whT,
    __half* __restrict__ zh, __half* __restrict__ xbch, float* __restrict__ xdt32) {
  __shared__ __align__(16) _Float16 sA[128 * 72];
  __shared__ __align__(16) _Float16 sB[128 * 72];
  int nt = blockIdx.x, mt = blockIdx.y;
  int m0 = mt * 128, n0 = nt * 128;
  int t = threadIdx.x, lane = t & 63, w = t >> 6;
  int acol = lane & 15, koff = (lane >> 4) * 8;
  int wr = w >> 1, wc = w & 1;
  f32x4 zz = {0.f, 0.f, 0.f, 0.f};
  f32x4 acc[4][4];
#pragma unroll
  for (int fr = 0; fr < 4; ++fr)
#pragma unroll
    for (int fc = 0; fc < 4; ++fc) acc[fr][fc] = zz;
  for (int kk = 0; kk < 3; ++kk) {
    if (kk) __syncthreads();
#pragma unroll
    for (int i = 0; i < 4; ++i) {
      int task = t + i * 256;
      int row = task >> 3, oct = task & 7;
      *(half8*)&sA[row * 72 + oct * 8] =
          *(const half8*)&uh[(size_t)(m0 + row) * 192 + kk * 64 + oct * 8];
      *(half8*)&sB[row * 72 + oct * 8] =
          *(const half8*)&whT[(size_t)(n0 + row) * 192 + kk * 64 + oct * 8];
    }
    __syncthreads();
#pragma unroll
    for (int ks = 0; ks < 2; ++ks) {
      half8 af[4], bf[4];
#pragma unroll
      for (int f = 0; f < 4; ++f) {
        af[f] = *(const half8*)&sA[(wr * 64 + f * 16 + acol) * 72 + ks * 32 + koff];
        bf[f] = *(const half8*)&sB[(wc * 64 + f * 16 + acol) * 72 + ks * 32 + koff];
      }
#pragma unroll
      for (int fr = 0; fr < 4; ++fr)
#pragma unroll
        for (int fc = 0; fc < 4; ++fc)
          acc[fr][fc] = __builtin_amdgcn_mfma_f32_16x16x32_f16(af[fr], bf[fc], acc[fr][fc], 0, 0, 0);
    }
  }
  int rb = (lane >> 4) * 4;
#pragma unroll
  for (int fr = 0; fr < 4; ++fr) {
#pragma unroll
    for (int fc = 0; fc < 4; ++fc) {
      int n = n0 + wc * 64 + fc * 16 + acol;
#pragma unroll
      for (int r = 0; r < 4; ++r) {
        int m = m0 + wr * 64 + fr * 16 + rb + r;
        float v = acc[fr][fc][r];
        if (n < DSSM) zh[(size_t)m * DSSM + n] = (__half)v;
        else if (n < 1024) xbch[(size_t)m * CH640 + (n - DSSM)] = (__half)v;
        else if (n < DIP) xdt32[(size_t)m * NHD + (n - 1024)] = v;
      }
    }
  }
}

// ---- 2. depthwise 3x3 conv + bias + SiLU (fp16 x/B/C input, fp32 dt input) ----
__global__ void k_conv(const __half* __restrict__ xbch, const float* __restrict__ xdt,
                       const float* __restrict__ cw, const float* __restrict__ cb,
                       __half* __restrict__ convh, float* __restrict__ dtraw) {
  int pid = blockIdx.x;  // b*4096 + p
  int b = pid >> 12, p = pid & 4095;
  int y = p >> 6, x = p & 63;
  int t = threadIdx.x;
  const __half* baseh = xbch + (size_t)b * LQ * CH640;
  const float* based = xdt + (size_t)b * LQ * NHD;
  for (int c = t; c < CCH; c += 256) {
    float s = 0.f;
#pragma unroll
    for (int ky = 0; ky < 3; ++ky) {
      int yy = y + ky - 1;
      if (yy < 0 || yy > 63) continue;
#pragma unroll
      for (int kx = 0; kx < 3; ++kx) {
        int xx = x + kx - 1;
        if (xx < 0 || xx > 63) continue;
        float iv = (c < CH640) ? (float)baseh[(size_t)(yy * 64 + xx) * CH640 + c]
                               : based[(size_t)(yy * 64 + xx) * NHD + (c - CH640)];
        s += iv * cw[c * 9 + ky * 3 + kx];
      }
    }
    float v = siluf(s + cb[c]);
    if (c < CH640) convh[(size_t)pid * CH640 + c] = (__half)v;
    else dtraw[(size_t)pid * NHD + (c - CH640)] = v;
  }
}

// ---- 3. dt softplus + per-chunk cumsum of dA (fp32 path) ----
__global__ void k_prep(const float* __restrict__ dtraw, const float* __restrict__ dt_bias,
                       const float* __restrict__ A_logs,
                       float* __restrict__ dtb, float* __restrict__ dacb) {
  __shared__ float sb[CLEN];
  int z = blockIdx.x, k = blockIdx.y, b = blockIdx.z;
  int s = threadIdx.x;
  int pixel = pixof(k, z * CLEN + s);
  const float* row = dtraw + ((size_t)(b * LQ + pixel)) * NHD;
  float raw[NHD];
#pragma unroll
  for (int h = 0; h < NHD; ++h) raw[h] = row[h];
  size_t base = (((size_t)(b * KDIR + k) * NCH + z) * NHD) * CLEN;
  for (int h = 0; h < NHD; ++h) {
    float dtv = softplusf(raw[h] + dt_bias[k * NHD + h]);
    float dA = dtv * (-expf(A_logs[k * NHD + h]));
    sb[s] = dA;
    __syncthreads();
    for (int off = 1; off < CLEN; off <<= 1) {
      float v = (s >= off) ? sb[s - off] : 0.f;
      __syncthreads();
      sb[s] += v;
      __syncthreads();
    }
    dtb[base + (size_t)h * CLEN + s] = dtv;
    dacb[base + (size_t)h * CLEN + s] = sb[s];
    __syncthreads();
  }
}

// ---- 4. CB = C @ B^T via fp16 MFMA, lower-triangle 64x64 tiles, fp16 out ----
__global__ __launch_bounds__(256, 4) void k_cb(const _Float16* __restrict__ convh,
                                               _Float16* __restrict__ cbuf) {
  __shared__ __align__(16) char smem[34816];
  _Float16* sCt = (_Float16*)smem;             // [64][136]
  _Float16* sBt = (_Float16*)(smem + 17408);   // [64][136]
  int pi = blockIdx.x, z = blockIdx.y, bk = blockIdx.z;
  int b = bk >> 2, kd = bk & 3;
  int SI = 0;
  while ((SI + 1) * (SI + 2) / 2 <= pi) ++SI;
  int SJ = pi - SI * (SI + 1) / 2;
  int t = threadIdx.x, lane = t & 63, w = t >> 6;
  int acol = lane & 15, koff = (lane >> 4) * 8;
  int R = w * 16, arow = R + acol, rbase = R + (lane >> 4) * 4;
  const _Float16* convb = convh + (size_t)b * LQ * CH640;
  for (int i = 0; i < 4; ++i) {
    int c = t + i * 256;
    int row = c >> 4, seg = c & 15;
    int pc = pixof(kd, z * CLEN + SI * 64 + row);
    *(half8*)&sCt[row * 136 + seg * 8] =
        *(const half8*)&convb[(size_t)pc * CH640 + (DSSM + DST) + seg * 8];
    int pbx = pixof(kd, z * CLEN + SJ * 64 + row);
    *(half8*)&sBt[row * 136 + seg * 8] =
        *(const half8*)&convb[(size_t)pbx * CH640 + DSSM + seg * 8];
  }
  __syncthreads();
  f32x4 zz = {0.f, 0.f, 0.f, 0.f};
  f32x4 acc[4] = {zz, zz, zz, zz};
  for (int ks = 0; ks < 4; ++ks) {
    half8 a = *(const half8*)&sCt[arow * 136 + ks * 32 + koff];
#pragma unroll
    for (int cg = 0; cg < 4; ++cg) {
      half8 bf = *(const half8*)&sBt[(cg * 16 + acol) * 136 + ks * 32 + koff];
      acc[cg] = __builtin_amdgcn_mfma_f32_16x16x32_f16(a, bf, acc[cg], 0, 0, 0);
    }
  }
  size_t base = ((size_t)(bk * NCH + z) * 10 + pi) * 4096;
#pragma unroll
  for (int cg = 0; cg < 4; ++cg)
#pragma unroll
    for (int r = 0; r < 4; ++r)
      cbuf[base + (size_t)(rbase + r) * 64 + cg * 16 + acol] = (_Float16)acc[cg][r];
}

// ---- 5. chunk states -> TRANSPOSED statesT[p][n] ----
__global__ void k_states(const _Float16* __restrict__ convh, const float* __restrict__ dtb,
                         const float* __restrict__ dacb, float* __restrict__ statesT) {
  __shared__ float sB[64 * 128];
  __shared__ float sX[64 * 64];
  __shared__ float sdt[CLEN];
  __shared__ float sdac[CLEN];
  int h = blockIdx.x, z = blockIdx.y, bk = blockIdx.z;
  int b = bk >> 2, kd = bk & 3;
  int t = threadIdx.x;
  size_t dbase = (((size_t)bk * NCH + z) * NHD + h) * CLEN;
  sdt[t] = dtb[dbase + t];
  sdac[t] = dacb[dbase + t];
  __syncthreads();
  float dac_last = sdac[CLEN - 1];
  int n = t & 127;
  int pb = (t >> 7) * 32;
  float acc[32];
#pragma unroll
  for (int jp = 0; jp < 32; ++jp) acc[jp] = 0.f;
  for (int st = 0; st < 4; ++st) {
    for (int e = t; e < 64 * 128; e += 256) {
      int ss = e >> 7, nn = e & 127;
      int pp = pixof(kd, z * CLEN + st * 64 + ss);
      sB[e] = (float)convh[((size_t)(b * LQ + pp)) * CH640 + DSSM + nn];
    }
    for (int e = t; e < 64 * 64; e += 256) {
      int ss = e >> 6, pp2 = e & 63;
      int sg = st * 64 + ss;
      int px = pixof(kd, z * CLEN + sg);
      float xvv = (float)convh[((size_t)(b * LQ + px)) * CH640 + h * 64 + pp2];
      sX[e] = xvv * sdt[sg] * __expf(dac_last - sdac[sg]);
    }
    __syncthreads();
    for (int ss = 0; ss < 64; ++ss) {
      float bv = sB[ss * 128 + n];
#pragma unroll
      for (int jp = 0; jp < 32; ++jp) acc[jp] += sX[ss * 64 + pb + jp] * bv;
    }
    __syncthreads();
  }
  size_t sbase = (((size_t)bk * NCH + z) * NHD + h) * (128 * 64);
#pragma unroll
  for (int jp = 0; jp < 32; ++jp) statesT[sbase + (size_t)(pb + jp) * 128 + n] = acc[jp];
}

// ---- 6. inter-chunk scan (in place, layout-agnostic) ----
__global__ void k_scan(float* __restrict__ states, const float* __restrict__ dacb) {
  int h = blockIdx.x, k = blockIdx.y, b = blockIdx.z;
  int bk = b * KDIR + k;
  int t = threadIdx.x;
  float carry[32];
#pragma unroll
  for (int j = 0; j < 32; ++j) carry[j] = 0.f;
  for (int z = 0; z < NCH; ++z) {
    float cd = __expf(dacb[(((size_t)bk * NCH + z) * NHD + h) * CLEN + (CLEN - 1)]);
    size_t sbase = (((size_t)bk * NCH + z) * NHD + h) * (128 * 64);
#pragma unroll
    for (int j = 0; j < 32; ++j) {
      size_t idx = sbase + (size_t)j * 256 + t;
      float sv = states[idx];
      states[idx] = carry[j];
      carry[j] = carry[j] * cd + sv;
    }
  }
}

// ---- 7. y via fp16 MFMA -> ybuf (per-direction, sequence-ordered, fp16) ----
__global__ __launch_bounds__(256, 4) void k_y(
    const _Float16* __restrict__ convh, const float* __restrict__ dtb,
    const float* __restrict__ dacb, const _Float16* __restrict__ cbuf,
    const float* __restrict__ prevT, const float* __restrict__ Ds,
    _Float16* __restrict__ ybuf) {
  __shared__ __align__(16) char smem[34816];
  __shared__ float sdt[CLEN], sdac[CLEN], sFac[CLEN];
  __shared__ float sExpD[64], sRs[64];
  _Float16* sC = (_Float16*)smem;              // phase A: [64][136]
  _Float16* sPrev = (_Float16*)(smem + 17408); // phase A: [64][136]
  _Float16* sA = (_Float16*)smem;              // phase B: [64][72]
  _Float16* sXW = (_Float16*)(smem + 9216);    // phase B: swizzled [64][64]

  int wg = blockIdx.x;  // 6144 = 8 XCD * 768
  int xid = (wg & 7) * 768 + (wg >> 3);
  int grp = xid / 24, i24 = xid % 24;
  int h = i24 >> 2, si_t = i24 & 3;
  int bk = grp >> 4, z = grp & 15;
  int b = bk >> 2, kd = bk & 3;
  int t = threadIdx.x;
  int lane = t & 63, w = t >> 6;
  int acol = lane & 15, koff = (lane >> 4) * 8;
  int R = w * 16, arow = R + acol, rbase = R + (lane >> 4) * 4;

  size_t dbase = (((size_t)bk * NCH + z) * NHD + h) * CLEN;
  sdt[t] = dtb[dbase + t];
  sdac[t] = dacb[dbase + t];
  __syncthreads();
  float ref = sdac[si_t * 64];
  sFac[t] = __expf(ref - sdac[t]);
  if (t < 64) {
    float d = sdac[si_t * 64 + t];
    sExpD[t] = __expf(d);
    sRs[t] = __expf(d - ref);
  }
  const _Float16* convb = convh + (size_t)b * LQ * CH640;
  // stage C tile [64 rows][128 n] fp16
  for (int i = 0; i < 4; ++i) {
    int c = t + i * 256;
    int row = c >> 4, seg = c & 15;
    int px = pixof(kd, z * CLEN + si_t * 64 + row);
    *(half8*)&sC[row * 136 + seg * 8] =
        *(const half8*)&convb[(size_t)px * CH640 + (DSSM + DST) + seg * 8];
  }
  // stage prevT fp32 -> fp16 [64 p][128 n]
  const float* pbp = prevT + (((size_t)bk * NCH + z) * NHD + h) * (128 * 64);
  for (int i = 0; i < 8; ++i) {
    int idx = t + i * 256;
    int p = idx >> 5, n0 = (idx & 31) * 4;
    float4 v = *(const float4*)&pbp[(size_t)p * 128 + n0];
    half4 hv;
    hv[0] = (_Float16)v.x; hv[1] = (_Float16)v.y;
    hv[2] = (_Float16)v.z; hv[3] = (_Float16)v.w;
    *(half4*)&sPrev[p * 136 + n0] = hv;
  }
  __syncthreads();
  // ---- y_inter: accE = C @ prev ----
  f32x4 zz = {0.f, 0.f, 0.f, 0.f};
  f32x4 accE[4] = {zz, zz, zz, zz};
  for (int ks = 0; ks < 4; ++ks) {
    half8 a = *(const half8*)&sC[arow * 136 + ks * 32 + koff];
#pragma unroll
    for (int cg = 0; cg < 4; ++cg) {
      half8 bf = *(const half8*)&sPrev[(cg * 16 + acol) * 136 + ks * 32 + koff];
      accE[cg] = __builtin_amdgcn_mfma_f32_16x16x32_f16(a, bf, accE[cg], 0, 0, 0);
    }
  }
  __syncthreads();  // phase A region dead; phase B may overwrite
  // ---- y_intra off-diagonal ----
  f32x4 accI[4] = {zz, zz, zz, zz};
  for (int SJ = 0; SJ < si_t; ++SJ) {
    for (int i = 0; i < 2; ++i) {
      int c = t + i * 256;
      int ss = c >> 3, pp0 = (c & 7) * 8;
      int sg = SJ * 64 + ss;
      int px = pixof(kd, z * CLEN + sg);
      half8 xv = *(const half8*)&convb[(size_t)px * CH640 + h * 64 + pp0];
      float f = sdt[sg] * sFac[sg];
#pragma unroll
      for (int u = 0; u < 8; ++u)
        sXW[XWI(pp0 + u, ss)] = (_Float16)((float)xv[u] * f);
    }
    __syncthreads();
    size_t cbase = ((size_t)(bk * NCH + z) * 10 + si_t * (si_t + 1) / 2 + SJ) * 4096;
#pragma unroll
    for (int ks = 0; ks < 2; ++ks) {
      half8 a = *(const half8*)&cbuf[cbase + (size_t)arow * 64 + ks * 32 + koff];
      int kso = ks * 4 + (lane >> 4);
#pragma unroll
      for (int cg = 0; cg < 4; ++cg) {
        int col = cg * 16 + acol;
        half8 bf = *(const half8*)&sXW[(col << 6) + ((kso ^ (col >> 3)) << 3)];
        accI[cg] = __builtin_amdgcn_mfma_f32_16x16x32_f16(a, bf, accI[cg], 0, 0, 0);
      }
    }
    __syncthreads();
  }
  // scale off-diag partial by per-row decay rs
  {
    float rsv[4];
#pragma unroll
    for (int r = 0; r < 4; ++r) rsv[r] = sRs[rbase + r];
#pragma unroll
    for (int cg = 0; cg < 4; ++cg)
#pragma unroll
      for (int r = 0; r < 4; ++r) accI[cg][r] *= rsv[r];
  }
  // ---- diagonal tile: decay+mask folded into A' ----
  {
    size_t cbase = ((size_t)(bk * NCH + z) * 10 + si_t * (si_t + 1) / 2 + si_t) * 4096;
    for (int i = 0; i < 16; ++i) {
      int e = t + i * 256;
      int sl = e >> 6, ss = e & 63;
      float cv = 0.f;
      if (ss <= sl)
        cv = (float)cbuf[cbase + e] * __expf(sdac[si_t * 64 + sl] - sdac[si_t * 64 + ss]);
      sA[sl * 72 + ss] = (_Float16)cv;
    }
    for (int i = 0; i < 2; ++i) {
      int c = t + i * 256;
      int ss = c >> 3, pp0 = (c & 7) * 8;
      int sg = si_t * 64 + ss;
      int px = pixof(kd, z * CLEN + sg);
      half8 xv = *(const half8*)&convb[(size_t)px * CH640 + h * 64 + pp0];
      float f = sdt[sg];
#pragma unroll
      for (int u = 0; u < 8; ++u)
        sXW[XWI(pp0 + u, ss)] = (_Float16)((float)xv[u] * f);
    }
    __syncthreads();
#pragma unroll
    for (int ks = 0; ks < 2; ++ks) {
      half8 a = *(const half8*)&sA[arow * 72 + ks * 32 + koff];
      int kso = ks * 4 + (lane >> 4);
#pragma unroll
      for (int cg = 0; cg < 4; ++cg) {
        int col = cg * 16 + acol;
        half8 bf = *(const half8*)&sXW[(col << 6) + ((kso ^ (col >> 3)) << 3)];
        accI[cg] = __builtin_amdgcn_mfma_f32_16x16x32_f16(a, bf, accI[cg], 0, 0, 0);
      }
    }
  }
  // ---- write: y = accI + exp(dac)*accE + D*x ----
  float dsv = Ds[kd * NHD + h];
  float eD[4];
#pragma unroll
  for (int r = 0; r < 4; ++r) eD[r] = sExpD[rbase + r];
#pragma unroll
  for (int cg = 0; cg < 4; ++cg) {
    int col = cg * 16 + acol;
#pragma unroll
    for (int r = 0; r < 4; ++r) {
      int row = rbase + r;
      int tg = z * CLEN + si_t * 64 + row;
      int px = pixof(kd, tg);
      float xv = (float)convb[(size_t)px * CH640 + h * 64 + col];
      float yv = accI[cg][r] + eD[r] * accE[cg][r] + dsv * xv;
      ybuf[((size_t)bk * LQ + tg) * DSSM + h * 64 + col] = (_Float16)yv;
    }
  }
}

// ---- 8. gather 4 directions + gated RMSNorm + out projection (8 px / block) ----
__global__ void k_final(const __half* __restrict__ yb, const __half* __restrict__ zh,
                        const float* __restrict__ norm_w, const float* __restrict__ Wout,
                        float* __restrict__ out) {
  __shared__ float sg[8 * DSSM];
  __shared__ float srstd[8];
  int m0 = blockIdx.x * 8;
  int t = threadIdx.x;
  for (int rr = 0; rr < 8; ++rr) {
    int m = m0 + rr, b = m >> 12, px = m & 4095;
    int tr = ((px & 63) << 6) | (px >> 6);
    int t0 = px, t1 = tr, t2 = 4095 - px, t3 = 4095 - tr;
    size_t b4 = (size_t)b * 4;
    for (int c = t; c < DSSM; c += 256) {
      float yv = (float)yb[((b4 + 0) * LQ + t0) * DSSM + c] +
                 (float)yb[((b4 + 1) * LQ + t1) * DSSM + c] +
                 (float)yb[((b4 + 2) * LQ + t2) * DSSM + c] +
                 (float)yb[((b4 + 3) * LQ + t3) * DSSM + c];
      float zv = (float)zh[(size_t)m * DSSM + c];
      sg[rr * DSSM + c] = yv * (zv / (1.f + __expf(-zv)));
    }
  }
  __syncthreads();
  {
    int r = t >> 5, j = t & 31;
    float s = 0.f;
    for (int c = j; c < DSSM; c += 32) { float g = sg[r * DSSM + c]; s += g * g; }
    s += __shfl_xor(s, 16, 32);
    s += __shfl_xor(s, 8, 32);
    s += __shfl_xor(s, 4, 32);
    s += __shfl_xor(s, 2, 32);
    s += __shfl_xor(s, 1, 32);
    if (j == 0) srstd[r] = rsqrtf(s / (float)DSSM + 1e-5f);
  }
  __syncthreads();
  for (int rr = 0; rr < 8; ++rr)
    for (int c = t; c < DSSM; c += 256) sg[rr * DSSM + c] *= srstd[rr] * norm_w[c];
  __syncthreads();
  if (t < DM) {
    float a[8];
#pragma unroll
    for (int rr = 0; rr < 8; ++rr) a[rr] = 0.f;
    for (int c = 0; c < DSSM; ++c) {
      float wv = Wout[(size_t)c * DM + t];
#pragma unroll
      for (int rr = 0; rr < 8; ++rr) a[rr] += sg[rr * DSSM + c] * wv;
    }
#pragma unroll
    for (int rr = 0; rr < 8; ++rr) out[(size_t)(m0 + rr) * DM + t] = a[rr];
  }
}

extern "C" void kernel_launch(void* const* d_in, const int* in_sizes, int n_in,
                              void* d_out, int out_size, void* d_ws, size_t ws_size,
                              hipStream_t stream) {
  const float* u = (const float*)d_in[0];
  const float* W_in = (const float*)d_in[1];
  const float* conv_w = (const float*)d_in[2];
  const float* conv_b = (const float*)d_in[3];
  const float* dt_bias = (const float*)d_in[4];
  const float* A_logs = (const float*)d_in[5];
  const float* Ds = (const float*)d_in[6];
  const float* norm_w = (const float*)d_in[7];
  const float* W_out = (const float*)d_in[8];
  float* out = (float*)d_out;

  float* ws = (float*)d_ws;
  size_t off = 0;
  __half* zh = (__half*)(ws + off); off += (size_t)BQ * LQ * DSSM / 2;
  _Float16* uh = (_Float16*)(ws + off); off += (size_t)UH_ELEMS / 2;
  _Float16* whT = (_Float16*)(ws + off); off += (size_t)WT_ELEMS / 2;
  __half* xbch = (__half*)(ws + off); off += (size_t)BQ * LQ * CH640 / 2;
  float* xdt32 = ws + off; off += (size_t)BQ * LQ * NHD;
  __half* convh = (__half*)(ws + off); off += (size_t)BQ * LQ * CH640 / 2;
  float* dtraw = ws + off; off += (size_t)BQ * LQ * NHD;
  float* dtb = ws + off; off += (size_t)BQ * KDIR * NCH * NHD * CLEN;
  float* dacb = ws + off; off += (size_t)BQ * KDIR * NCH * NHD * CLEN;
  float* statesT = ws + off; off += (size_t)BQ * KDIR * NCH * NHD * 128 * 64;
  __half* ybuf = (__half*)(ws + off); off += (size_t)BQ * KDIR * LQ * DSSM / 2;
  _Float16* cbuf = (_Float16*)xbch;  // alias: xbch dead after k_conv (10,485,760 halves each)

  k_cvt<<<(UH_ELEMS + WT_ELEMS) / 256, 256, 0, stream>>>(u, W_in, uh, whT);
  k_inproj<<<dim3(9, 128), 256, 0, stream>>>(uh, whT, zh, xbch, xdt32);
  k_conv<<<BQ * LQ, 256, 0, stream>>>(xbch, xdt32, conv_w, conv_b, convh, dtraw);
  k_prep<<<dim3(NCH, KDIR, BQ), 256, 0, stream>>>(dtraw, dt_bias, A_logs, dtb, dacb);
  k_cb<<<dim3(10, NCH, BQ * KDIR), 256, 0, stream>>>((const _Float16*)convh, cbuf);
  k_states<<<dim3(NHD, NCH, BQ * KDIR), 256, 0, stream>>>((const _Float16*)convh, dtb, dacb, statesT);
  k_scan<<<dim3(NHD, KDIR, BQ), 256, 0, stream>>>(statesT, dacb);
  k_y<<<KDIR * NHD * 4 * NCH * BQ, 256, 0, stream>>>((const _Float16*)convh, dtb, dacb,
                                                     (const _Float16*)cbuf, statesT, Ds,
                                                     (_Float16*)ybuf);
  k_final<<<BQ * LQ / 8, 256, 0, stream>>>(ybuf, zh, norm_w, W_out, out);
}

// Round 7
// 479.968 us; speedup vs baseline: 5.0476x; 1.3796x over previous
//
#include <hip/hip_runtime.h>
#include <hip/hip_fp16.h>
#include <math.h>

#define BQ 4
#define LQ 4096
#define DM 192
#define DIP 1030
#define DSSM 384
#define DST 128
#define CCH 646
#define CH640 640
#define NHD 6
#define KDIR 4
#define NCH 16
#define CLEN 256
#define UH_ELEMS (16384 * 192)
#define WT_ELEMS (1152 * 192)

using half8 = __attribute__((ext_vector_type(8))) _Float16;
using half4 = __attribute__((ext_vector_type(4))) _Float16;
using f32x4 = __attribute__((ext_vector_type(4))) float;

// Transpose-staging layout: row stride 72 halves (36 dwords = +4 bank rotation/row)
// + XOR of s-octet with row-octet. Conflict-free b16 scatter-writes AND b128 reads.
#define XWI(pp, ss) ((pp) * 72 + ((((ss) >> 3) ^ ((pp) >> 3)) << 3) + ((ss) & 7))
#define XW2(n, ss) ((n) * 72 + (((((ss) >> 3) ^ ((n) >> 3)) & 7) << 3) + ((ss) & 7))

__device__ __forceinline__ int pixof(int k, int t) {
  switch (k) {
    case 0: return t;
    case 1: return ((t & 63) << 6) | (t >> 6);
    case 2: return 4095 - t;
    default: { int tp = 4095 - t; return ((tp & 63) << 6) | (tp >> 6); }
  }
}

__device__ __forceinline__ float softplusf(float x) {
  return (x > 20.f) ? x : log1pf(expf(x));
}
__device__ __forceinline__ float siluf(float x) {
  return x / (1.f + __expf(-x));
}

// ---- 0. convert u -> fp16, W_in -> fp16 transposed [1152][192], zero-padded ----
__global__ void k_cvt(const float* __restrict__ u, const float* __restrict__ W,
                      _Float16* __restrict__ uh, _Float16* __restrict__ whT) {
  int idx = blockIdx.x * 256 + threadIdx.x;
  if (idx < UH_ELEMS) uh[idx] = (_Float16)u[idx];
  int widx = idx - UH_ELEMS;
  if (widx >= 0 && widx < WT_ELEMS) {
    int n = widx / 192, kk = widx - n * 192;
    whT[widx] = (n < DIP) ? (_Float16)W[(size_t)kk * DIP + n] : (_Float16)0.f;
  }
}

// ---- 1. in_proj via fp16 MFMA: (16384,192)@(192,1152) -> zh | xbch | xdt32 ----
__global__ __launch_bounds__(256) void k_inproj(
    const _Float16* __restrict__ uh, const _Float16* __restrict__ whT,
    __half* __restrict__ zh, __half* __restrict__ xbch, float* __restrict__ xdt32) {
  __shared__ __align__(16) _Float16 sA[128 * 72];
  __shared__ __align__(16) _Float16 sB[128 * 72];
  int nt = blockIdx.x, mt = blockIdx.y;
  int m0 = mt * 128, n0 = nt * 128;
  int t = threadIdx.x, lane = t & 63, w = t >> 6;
  int acol = lane & 15, koff = (lane >> 4) * 8;
  int wr = w >> 1, wc = w & 1;
  f32x4 zz = {0.f, 0.f, 0.f, 0.f};
  f32x4 acc[4][4];
#pragma unroll
  for (int fr = 0; fr < 4; ++fr)
#pragma unroll
    for (int fc = 0; fc < 4; ++fc) acc[fr][fc] = zz;
  for (int kk = 0; kk < 3; ++kk) {
    if (kk) __syncthreads();
#pragma unroll
    for (int i = 0; i < 4; ++i) {
      int task = t + i * 256;
      int row = task >> 3, oct = task & 7;
      *(half8*)&sA[row * 72 + oct * 8] =
          *(const half8*)&uh[(size_t)(m0 + row) * 192 + kk * 64 + oct * 8];
      *(half8*)&sB[row * 72 + oct * 8] =
          *(const half8*)&whT[(size_t)(n0 + row) * 192 + kk * 64 + oct * 8];
    }
    __syncthreads();
#pragma unroll
    for (int ks = 0; ks < 2; ++ks) {
      half8 af[4], bf[4];
#pragma unroll
      for (int f = 0; f < 4; ++f) {
        af[f] = *(const half8*)&sA[(wr * 64 + f * 16 + acol) * 72 + ks * 32 + koff];
        bf[f] = *(const half8*)&sB[(wc * 64 + f * 16 + acol) * 72 + ks * 32 + koff];
      }
#pragma unroll
      for (int fr = 0; fr < 4; ++fr)
#pragma unroll
        for (int fc = 0; fc < 4; ++fc)
          acc[fr][fc] = __builtin_amdgcn_mfma_f32_16x16x32_f16(af[fr], bf[fc], acc[fr][fc], 0, 0, 0);
    }
  }
  int rb = (lane >> 4) * 4;
#pragma unroll
  for (int fr = 0; fr < 4; ++fr) {
#pragma unroll
    for (int fc = 0; fc < 4; ++fc) {
      int n = n0 + wc * 64 + fc * 16 + acol;
#pragma unroll
      for (int r = 0; r < 4; ++r) {
        int m = m0 + wr * 64 + fr * 16 + rb + r;
        float v = acc[fr][fc][r];
        if (n < DSSM) zh[(size_t)m * DSSM + n] = (__half)v;
        else if (n < 1024) xbch[(size_t)m * CH640 + (n - DSSM)] = (__half)v;
        else if (n < DIP) xdt32[(size_t)m * NHD + (n - 1024)] = v;
      }
    }
  }
}

// ---- 2. depthwise 3x3 conv + bias + SiLU (half2-vectorized) ----
__global__ void k_conv(const __half* __restrict__ xbch, const float* __restrict__ xdt,
                       const float* __restrict__ cw, const float* __restrict__ cb,
                       __half* __restrict__ convh, float* __restrict__ dtraw) {
  int pid = blockIdx.x;  // b*4096 + p
  int b = pid >> 12, p = pid & 4095;
  int y = p >> 6, x = p & 63;
  int t = threadIdx.x;
  const __half2* baseh2 = (const __half2*)(xbch + (size_t)b * LQ * CH640);
  __half2* outh2 = (__half2*)(convh + (size_t)pid * CH640);
  for (int pc = t; pc < 320; pc += 256) {
    int c0 = pc * 2;
    float s0 = 0.f, s1 = 0.f;
#pragma unroll
    for (int ky = 0; ky < 3; ++ky) {
      int yy = y + ky - 1;
      if (yy < 0 || yy > 63) continue;
#pragma unroll
      for (int kx = 0; kx < 3; ++kx) {
        int xx = x + kx - 1;
        if (xx < 0 || xx > 63) continue;
        __half2 v = baseh2[(size_t)(yy * 64 + xx) * 320 + pc];
        int wi = ky * 3 + kx;
        s0 += (float)v.x * cw[c0 * 9 + wi];
        s1 += (float)v.y * cw[(c0 + 1) * 9 + wi];
      }
    }
    __half2 o;
    o.x = (__half)siluf(s0 + cb[c0]);
    o.y = (__half)siluf(s1 + cb[c0 + 1]);
    outh2[pc] = o;
  }
  if (t < NHD) {
    const float* based = xdt + (size_t)b * LQ * NHD;
    float s = 0.f;
#pragma unroll
    for (int ky = 0; ky < 3; ++ky) {
      int yy = y + ky - 1;
      if (yy < 0 || yy > 63) continue;
#pragma unroll
      for (int kx = 0; kx < 3; ++kx) {
        int xx = x + kx - 1;
        if (xx < 0 || xx > 63) continue;
        s += based[(size_t)(yy * 64 + xx) * NHD + t] * cw[(CH640 + t) * 9 + ky * 3 + kx];
      }
    }
    dtraw[(size_t)pid * NHD + t] = siluf(s + cb[CH640 + t]);
  }
}

// ---- 3. dt softplus + per-chunk cumsum of dA (fp32 path) ----
__global__ void k_prep(const float* __restrict__ dtraw, const float* __restrict__ dt_bias,
                       const float* __restrict__ A_logs,
                       float* __restrict__ dtb, float* __restrict__ dacb) {
  __shared__ float sb[CLEN];
  int z = blockIdx.x, k = blockIdx.y, b = blockIdx.z;
  int s = threadIdx.x;
  int pixel = pixof(k, z * CLEN + s);
  const float* row = dtraw + ((size_t)(b * LQ + pixel)) * NHD;
  float raw[NHD];
#pragma unroll
  for (int h = 0; h < NHD; ++h) raw[h] = row[h];
  size_t base = (((size_t)(b * KDIR + k) * NCH + z) * NHD) * CLEN;
  for (int h = 0; h < NHD; ++h) {
    float dtv = softplusf(raw[h] + dt_bias[k * NHD + h]);
    float dA = dtv * (-expf(A_logs[k * NHD + h]));
    sb[s] = dA;
    __syncthreads();
    for (int off = 1; off < CLEN; off <<= 1) {
      float v = (s >= off) ? sb[s - off] : 0.f;
      __syncthreads();
      sb[s] += v;
      __syncthreads();
    }
    dtb[base + (size_t)h * CLEN + s] = dtv;
    dacb[base + (size_t)h * CLEN + s] = sb[s];
    __syncthreads();
  }
}

// ---- 4. CB = C @ B^T via fp16 MFMA, lower-triangle 64x64 tiles, fp16 out ----
__global__ __launch_bounds__(256, 4) void k_cb(const _Float16* __restrict__ convh,
                                               _Float16* __restrict__ cbuf) {
  __shared__ __align__(16) char smem[34816];
  _Float16* sCt = (_Float16*)smem;             // [64][136]
  _Float16* sBt = (_Float16*)(smem + 17408);   // [64][136]
  int pi = blockIdx.x, z = blockIdx.y, bk = blockIdx.z;
  int b = bk >> 2, kd = bk & 3;
  int SI = 0;
  while ((SI + 1) * (SI + 2) / 2 <= pi) ++SI;
  int SJ = pi - SI * (SI + 1) / 2;
  int t = threadIdx.x, lane = t & 63, w = t >> 6;
  int acol = lane & 15, koff = (lane >> 4) * 8;
  int R = w * 16, arow = R + acol, rbase = R + (lane >> 4) * 4;
  const _Float16* convb = convh + (size_t)b * LQ * CH640;
  for (int i = 0; i < 4; ++i) {
    int c = t + i * 256;
    int row = c >> 4, seg = c & 15;
    int pc = pixof(kd, z * CLEN + SI * 64 + row);
    *(half8*)&sCt[row * 136 + seg * 8] =
        *(const half8*)&convb[(size_t)pc * CH640 + (DSSM + DST) + seg * 8];
    int pbx = pixof(kd, z * CLEN + SJ * 64 + row);
    *(half8*)&sBt[row * 136 + seg * 8] =
        *(const half8*)&convb[(size_t)pbx * CH640 + DSSM + seg * 8];
  }
  __syncthreads();
  f32x4 zz = {0.f, 0.f, 0.f, 0.f};
  f32x4 acc[4] = {zz, zz, zz, zz};
  for (int ks = 0; ks < 4; ++ks) {
    half8 a = *(const half8*)&sCt[arow * 136 + ks * 32 + koff];
#pragma unroll
    for (int cg = 0; cg < 4; ++cg) {
      half8 bf = *(const half8*)&sBt[(cg * 16 + acol) * 136 + ks * 32 + koff];
      acc[cg] = __builtin_amdgcn_mfma_f32_16x16x32_f16(a, bf, acc[cg], 0, 0, 0);
    }
  }
  size_t base = ((size_t)(bk * NCH + z) * 10 + pi) * 4096;
#pragma unroll
  for (int cg = 0; cg < 4; ++cg)
#pragma unroll
    for (int r = 0; r < 4; ++r)
      cbuf[base + (size_t)(rbase + r) * 64 + cg * 16 + acol] = (_Float16)acc[cg][r];
}

// ---- 5. chunk states via fp16 MFMA -> statesT[p][n] fp32 ----
__global__ __launch_bounds__(256, 4) void k_states(
    const _Float16* __restrict__ convh, const float* __restrict__ dtb,
    const float* __restrict__ dacb, float* __restrict__ statesT) {
  __shared__ __align__(16) _Float16 sA[64 * 72];    // XW^T [p][s] swizzled
  __shared__ __align__(16) _Float16 sB2[128 * 72];  // B^T [n][s] swizzled
  __shared__ float sFac[CLEN];
  int h = blockIdx.x, z = blockIdx.y, bk = blockIdx.z;
  int b = bk >> 2, kd = bk & 3;
  int t = threadIdx.x, lane = t & 63, w = t >> 6;
  int acol = lane & 15, koct = lane >> 4;
  size_t dbase = (((size_t)bk * NCH + z) * NHD + h) * CLEN;
  {
    float dac_last = dacb[dbase + CLEN - 1];
    sFac[t] = dtb[dbase + t] * __expf(dac_last - dacb[dbase + t]);
  }
  __syncthreads();
  const _Float16* convb = convh + (size_t)b * LQ * CH640;
  f32x4 zz = {0.f, 0.f, 0.f, 0.f};
  f32x4 acc[8] = {zz, zz, zz, zz, zz, zz, zz, zz};
  for (int st = 0; st < 4; ++st) {
    if (st) __syncthreads();
    // stage A' = XW^T: 64 s x 64 p (tasks: 64 ss x 8 p-octets)
#pragma unroll
    for (int i = 0; i < 2; ++i) {
      int c = t + i * 256;
      int ss = c >> 3, pp0 = (c & 7) * 8;
      int sg = st * 64 + ss;
      int px = pixof(kd, z * CLEN + sg);
      half8 xv = *(const half8*)&convb[(size_t)px * CH640 + h * 64 + pp0];
      float f = sFac[sg];
#pragma unroll
      for (int u = 0; u < 8; ++u) sA[XWI(pp0 + u, ss)] = (_Float16)((float)xv[u] * f);
    }
    // stage B' = Bmat^T: 64 s x 128 n (tasks: 64 ss x 16 n-octets)
#pragma unroll
    for (int i = 0; i < 4; ++i) {
      int c = t + i * 256;
      int ss = c >> 4, n0 = (c & 15) * 8;
      int sg = st * 64 + ss;
      int px = pixof(kd, z * CLEN + sg);
      half8 bv = *(const half8*)&convb[(size_t)px * CH640 + DSSM + n0];
#pragma unroll
      for (int u = 0; u < 8; ++u) sB2[XW2(n0 + u, ss)] = bv[u];
    }
    __syncthreads();
#pragma unroll
    for (int ks = 0; ks < 2; ++ks) {
      int kso = ks * 4 + koct;
      int arow = w * 16 + acol;
      half8 a = *(const half8*)&sA[arow * 72 + ((kso ^ (arow >> 3)) << 3)];
#pragma unroll
      for (int nf = 0; nf < 8; ++nf) {
        int col = nf * 16 + acol;
        half8 bf = *(const half8*)&sB2[col * 72 + (((kso ^ (col >> 3)) & 7) << 3)];
        acc[nf] = __builtin_amdgcn_mfma_f32_16x16x32_f16(a, bf, acc[nf], 0, 0, 0);
      }
    }
  }
  size_t sbase = (((size_t)bk * NCH + z) * NHD + h) * (128 * 64);
  int rbase = koct * 4;
#pragma unroll
  for (int nf = 0; nf < 8; ++nf) {
    int col = nf * 16 + acol;
#pragma unroll
    for (int r = 0; r < 4; ++r)
      statesT[sbase + (size_t)(w * 16 + rbase + r) * 128 + col] = acc[nf][r];
  }
}

// ---- 6. inter-chunk scan (in place, layout-agnostic) ----
__global__ void k_scan(float* __restrict__ states, const float* __restrict__ dacb) {
  int h = blockIdx.x, k = blockIdx.y, b = blockIdx.z;
  int bk = b * KDIR + k;
  int t = threadIdx.x;
  float carry[32];
#pragma unroll
  for (int j = 0; j < 32; ++j) carry[j] = 0.f;
  for (int z = 0; z < NCH; ++z) {
    float cd = __expf(dacb[(((size_t)bk * NCH + z) * NHD + h) * CLEN + (CLEN - 1)]);
    size_t sbase = (((size_t)bk * NCH + z) * NHD + h) * (128 * 64);
#pragma unroll
    for (int j = 0; j < 32; ++j) {
      size_t idx = sbase + (size_t)j * 256 + t;
      float sv = states[idx];
      states[idx] = carry[j];
      carry[j] = carry[j] * cd + sv;
    }
  }
}

// ---- 7. y via fp16 MFMA -> ybuf (per-direction, sequence-ordered, fp16) ----
__global__ __launch_bounds__(256, 4) void k_y(
    const _Float16* __restrict__ convh, const float* __restrict__ dtb,
    const float* __restrict__ dacb, const _Float16* __restrict__ cbuf,
    const float* __restrict__ prevT, const float* __restrict__ Ds,
    _Float16* __restrict__ ybuf) {
  __shared__ __align__(16) char smem[34816];
  __shared__ float sdt[CLEN], sdac[CLEN], sFac[CLEN];
  __shared__ float sExpD[64], sRs[64];
  _Float16* sC = (_Float16*)smem;              // phase A: [64][136]
  _Float16* sPrev = (_Float16*)(smem + 17408); // phase A: [64][136]
  _Float16* sA = (_Float16*)smem;              // phase B: [64][72]
  _Float16* sXW = (_Float16*)(smem + 9216);    // phase B: swizzled [64][72]

  int wg = blockIdx.x;  // 6144 = 8 XCD * 768
  int xid = (wg & 7) * 768 + (wg >> 3);
  int grp = xid / 24, i24 = xid % 24;
  int h = i24 >> 2, si_t = i24 & 3;
  int bk = grp >> 4, z = grp & 15;
  int b = bk >> 2, kd = bk & 3;
  int t = threadIdx.x;
  int lane = t & 63, w = t >> 6;
  int acol = lane & 15, koff = (lane >> 4) * 8;
  int R = w * 16, arow = R + acol, rbase = R + (lane >> 4) * 4;

  size_t dbase = (((size_t)bk * NCH + z) * NHD + h) * CLEN;
  sdt[t] = dtb[dbase + t];
  sdac[t] = dacb[dbase + t];
  __syncthreads();
  float ref = sdac[si_t * 64];
  sFac[t] = __expf(ref - sdac[t]);
  if (t < 64) {
    float d = sdac[si_t * 64 + t];
    sExpD[t] = __expf(d);
    sRs[t] = __expf(d - ref);
  }
  const _Float16* convb = convh + (size_t)b * LQ * CH640;
  // stage C tile [64 rows][128 n] fp16
  for (int i = 0; i < 4; ++i) {
    int c = t + i * 256;
    int row = c >> 4, seg = c & 15;
    int px = pixof(kd, z * CLEN + si_t * 64 + row);
    *(half8*)&sC[row * 136 + seg * 8] =
        *(const half8*)&convb[(size_t)px * CH640 + (DSSM + DST) + seg * 8];
  }
  // stage prevT fp32 -> fp16 [64 p][128 n]
  const float* pbp = prevT + (((size_t)bk * NCH + z) * NHD + h) * (128 * 64);
  for (int i = 0; i < 8; ++i) {
    int idx = t + i * 256;
    int p = idx >> 5, n0 = (idx & 31) * 4;
    float4 v = *(const float4*)&pbp[(size_t)p * 128 + n0];
    half4 hv;
    hv[0] = (_Float16)v.x; hv[1] = (_Float16)v.y;
    hv[2] = (_Float16)v.z; hv[3] = (_Float16)v.w;
    *(half4*)&sPrev[p * 136 + n0] = hv;
  }
  __syncthreads();
  // ---- y_inter: accE = C @ prev ----
  f32x4 zz = {0.f, 0.f, 0.f, 0.f};
  f32x4 accE[4] = {zz, zz, zz, zz};
  for (int ks = 0; ks < 4; ++ks) {
    half8 a = *(const half8*)&sC[arow * 136 + ks * 32 + koff];
#pragma unroll
    for (int cg = 0; cg < 4; ++cg) {
      half8 bf = *(const half8*)&sPrev[(cg * 16 + acol) * 136 + ks * 32 + koff];
      accE[cg] = __builtin_amdgcn_mfma_f32_16x16x32_f16(a, bf, accE[cg], 0, 0, 0);
    }
  }
  __syncthreads();  // phase A region dead; phase B may overwrite
  // ---- y_intra off-diagonal ----
  f32x4 accI[4] = {zz, zz, zz, zz};
  for (int SJ = 0; SJ < si_t; ++SJ) {
    for (int i = 0; i < 2; ++i) {
      int c = t + i * 256;
      int ss = c >> 3, pp0 = (c & 7) * 8;
      int sg = SJ * 64 + ss;
      int px = pixof(kd, z * CLEN + sg);
      half8 xv = *(const half8*)&convb[(size_t)px * CH640 + h * 64 + pp0];
      float f = sdt[sg] * sFac[sg];
#pragma unroll
      for (int u = 0; u < 8; ++u)
        sXW[XWI(pp0 + u, ss)] = (_Float16)((float)xv[u] * f);
    }
    __syncthreads();
    size_t cbase = ((size_t)(bk * NCH + z) * 10 + si_t * (si_t + 1) / 2 + SJ) * 4096;
#pragma unroll
    for (int ks = 0; ks < 2; ++ks) {
      half8 a = *(const half8*)&cbuf[cbase + (size_t)arow * 64 + ks * 32 + koff];
      int kso = ks * 4 + (lane >> 4);
#pragma unroll
      for (int cg = 0; cg < 4; ++cg) {
        int col = cg * 16 + acol;
        half8 bf = *(const half8*)&sXW[col * 72 + ((kso ^ (col >> 3)) << 3)];
        accI[cg] = __builtin_amdgcn_mfma_f32_16x16x32_f16(a, bf, accI[cg], 0, 0, 0);
      }
    }
    __syncthreads();
  }
  // scale off-diag partial by per-row decay rs
  {
    float rsv[4];
#pragma unroll
    for (int r = 0; r < 4; ++r) rsv[r] = sRs[rbase + r];
#pragma unroll
    for (int cg = 0; cg < 4; ++cg)
#pragma unroll
      for (int r = 0; r < 4; ++r) accI[cg][r] *= rsv[r];
  }
  // ---- diagonal tile: decay+mask folded into A' ----
  {
    size_t cbase = ((size_t)(bk * NCH + z) * 10 + si_t * (si_t + 1) / 2 + si_t) * 4096;
    for (int i = 0; i < 16; ++i) {
      int e = t + i * 256;
      int sl = e >> 6, ss = e & 63;
      float cv = 0.f;
      if (ss <= sl)
        cv = (float)cbuf[cbase + e] * __expf(sdac[si_t * 64 + sl] - sdac[si_t * 64 + ss]);
      sA[sl * 72 + ss] = (_Float16)cv;
    }
    for (int i = 0; i < 2; ++i) {
      int c = t + i * 256;
      int ss = c >> 3, pp0 = (c & 7) * 8;
      int sg = si_t * 64 + ss;
      int px = pixof(kd, z * CLEN + sg);
      half8 xv = *(const half8*)&convb[(size_t)px * CH640 + h * 64 + pp0];
      float f = sdt[sg];
#pragma unroll
      for (int u = 0; u < 8; ++u)
        sXW[XWI(pp0 + u, ss)] = (_Float16)((float)xv[u] * f);
    }
    __syncthreads();
#pragma unroll
    for (int ks = 0; ks < 2; ++ks) {
      half8 a = *(const half8*)&sA[arow * 72 + ks * 32 + koff];
      int kso = ks * 4 + (lane >> 4);
#pragma unroll
      for (int cg = 0; cg < 4; ++cg) {
        int col = cg * 16 + acol;
        half8 bf = *(const half8*)&sXW[col * 72 + ((kso ^ (col >> 3)) << 3)];
        accI[cg] = __builtin_amdgcn_mfma_f32_16x16x32_f16(a, bf, accI[cg], 0, 0, 0);
      }
    }
  }
  // ---- write: y = accI + exp(dac)*accE + D*x ----
  float dsv = Ds[kd * NHD + h];
  float eD[4];
#pragma unroll
  for (int r = 0; r < 4; ++r) eD[r] = sExpD[rbase + r];
#pragma unroll
  for (int cg = 0; cg < 4; ++cg) {
    int col = cg * 16 + acol;
#pragma unroll
    for (int r = 0; r < 4; ++r) {
      int row = rbase + r;
      int tg = z * CLEN + si_t * 64 + row;
      int px = pixof(kd, tg);
      float xv = (float)convb[(size_t)px * CH640 + h * 64 + col];
      float yv = accI[cg][r] + eD[r] * accE[cg][r] + dsv * xv;
      ybuf[((size_t)bk * LQ + tg) * DSSM + h * 64 + col] = (_Float16)yv;
    }
  }
}

// ---- 8. gather 4 directions + gated RMSNorm + out projection (8 px / block) ----
__global__ void k_final(const __half* __restrict__ yb, const __half* __restrict__ zh,
                        const float* __restrict__ norm_w, const float* __restrict__ Wout,
                        float* __restrict__ out) {
  __shared__ float sg[8 * DSSM];
  __shared__ float srstd[8];
  int m0 = blockIdx.x * 8;
  int t = threadIdx.x;
  for (int rr = 0; rr < 8; ++rr) {
    int m = m0 + rr, b = m >> 12, px = m & 4095;
    int tr = ((px & 63) << 6) | (px >> 6);
    int t0 = px, t1 = tr, t2 = 4095 - px, t3 = 4095 - tr;
    size_t b4 = (size_t)b * 4;
    for (int c = t; c < DSSM; c += 256) {
      float yv = (float)yb[((b4 + 0) * LQ + t0) * DSSM + c] +
                 (float)yb[((b4 + 1) * LQ + t1) * DSSM + c] +
                 (float)yb[((b4 + 2) * LQ + t2) * DSSM + c] +
                 (float)yb[((b4 + 3) * LQ + t3) * DSSM + c];
      float zv = (float)zh[(size_t)m * DSSM + c];
      sg[rr * DSSM + c] = yv * (zv / (1.f + __expf(-zv)));
    }
  }
  __syncthreads();
  {
    int r = t >> 5, j = t & 31;
    float s = 0.f;
    for (int c = j; c < DSSM; c += 32) { float g = sg[r * DSSM + c]; s += g * g; }
    s += __shfl_xor(s, 16, 32);
    s += __shfl_xor(s, 8, 32);
    s += __shfl_xor(s, 4, 32);
    s += __shfl_xor(s, 2, 32);
    s += __shfl_xor(s, 1, 32);
    if (j == 0) srstd[r] = rsqrtf(s / (float)DSSM + 1e-5f);
  }
  __syncthreads();
  for (int rr = 0; rr < 8; ++rr)
    for (int c = t; c < DSSM; c += 256) sg[rr * DSSM + c] *= srstd[rr] * norm_w[c];
  __syncthreads();
  if (t < DM) {
    float a[8];
#pragma unroll
    for (int rr = 0; rr < 8; ++rr) a[rr] = 0.f;
    for (int c = 0; c < DSSM; ++c) {
      float wv = Wout[(size_t)c * DM + t];
#pragma unroll
      for (int rr = 0; rr < 8; ++rr) a[rr] += sg[rr * DSSM + c] * wv;
    }
#pragma unroll
    for (int rr = 0; rr < 8; ++rr) out[(size_t)(m0 + rr) * DM + t] = a[rr];
  }
}

extern "C" void kernel_launch(void* const* d_in, const int* in_sizes, int n_in,
                              void* d_out, int out_size, void* d_ws, size_t ws_size,
                              hipStream_t stream) {
  const float* u = (const float*)d_in[0];
  const float* W_in = (const float*)d_in[1];
  const float* conv_w = (const float*)d_in[2];
  const float* conv_b = (const float*)d_in[3];
  const float* dt_bias = (const float*)d_in[4];
  const float* A_logs = (const float*)d_in[5];
  const float* Ds = (const float*)d_in[6];
  const float* norm_w = (const float*)d_in[7];
  const float* W_out = (const float*)d_in[8];
  float* out = (float*)d_out;

  float* ws = (float*)d_ws;
  size_t off = 0;
  __half* zh = (__half*)(ws + off); off += (size_t)BQ * LQ * DSSM / 2;
  _Float16* uh = (_Float16*)(ws + off); off += (size_t)UH_ELEMS / 2;
  _Float16* whT = (_Float16*)(ws + off); off += (size_t)WT_ELEMS / 2;
  __half* xbch = (__half*)(ws + off); off += (size_t)BQ * LQ * CH640 / 2;
  float* xdt32 = ws + off; off += (size_t)BQ * LQ * NHD;
  __half* convh = (__half*)(ws + off); off += (size_t)BQ * LQ * CH640 / 2;
  float* dtraw = ws + off; off += (size_t)BQ * LQ * NHD;
  float* dtb = ws + off; off += (size_t)BQ * KDIR * NCH * NHD * CLEN;
  float* dacb = ws + off; off += (size_t)BQ * KDIR * NCH * NHD * CLEN;
  float* statesT = ws + off; off += (size_t)BQ * KDIR * NCH * NHD * 128 * 64;
  __half* ybuf = (__half*)(ws + off); off += (size_t)BQ * KDIR * LQ * DSSM / 2;
  _Float16* cbuf = (_Float16*)xbch;  // alias: xbch dead after k_conv (10,485,760 halves each)

  k_cvt<<<(UH_ELEMS + WT_ELEMS) / 256, 256, 0, stream>>>(u, W_in, uh, whT);
  k_inproj<<<dim3(9, 128), 256, 0, stream>>>(uh, whT, zh, xbch, xdt32);
  k_conv<<<BQ * LQ, 256, 0, stream>>>(xbch, xdt32, conv_w, conv_b, convh, dtraw);
  k_prep<<<dim3(NCH, KDIR, BQ), 256, 0, stream>>>(dtraw, dt_bias, A_logs, dtb, dacb);
  k_cb<<<dim3(10, NCH, BQ * KDIR), 256, 0, stream>>>((const _Float16*)convh, cbuf);
  k_states<<<dim3(NHD, NCH, BQ * KDIR), 256, 0, stream>>>((const _Float16*)convh, dtb, dacb, statesT);
  k_scan<<<dim3(NHD, KDIR, BQ), 256, 0, stream>>>(statesT, dacb);
  k_y<<<KDIR * NHD * 4 * NCH * BQ, 256, 0, stream>>>((const _Float16*)convh, dtb, dacb,
                                                     (const _Float16*)cbuf, statesT, Ds,
                                                     (_Float16*)ybuf);
  k_final<<<BQ * LQ / 8, 256, 0, stream>>>(ybuf, zh, norm_w, W_out, out);
}